// Round 3
// baseline (238.757 us; speedup 1.0000x reference)
//
#include <hip/hip_runtime.h>

// FocusedLinearAttention — fully fused single kernel, MI355X gfx950.
// Inputs/outputs are FLOAT32 on device; harness threshold = 2% of max|ref|.
// Round-3 change: double-bf16 (hi+lo split) GEMMs for q/k/v to kill the
// bf16-rounding error that the focusing cube amplifies 3x. Structure otherwise
// identical to round 2 (which scored absmax 4.49e-2 ~= pure rounding error).
//
// MFMA layout (gfx950 v_mfma_f32_16x16x32_bf16):
//   A frag: lane l elem j -> A[m = l&15][k = 8*(l>>4) + j]
//   B frag: lane l elem j -> B[k = 8*(l>>4) + j][n = l&15]
//   C/D   : lane l reg  r -> D[m = 4*(l>>4) + r][n = l&15]

typedef float f32x4 __attribute__((ext_vector_type(4)));
typedef short bf8v  __attribute__((ext_vector_type(8)));
typedef short bf4v  __attribute__((ext_vector_type(4)));
typedef unsigned short u16;

#define MFMA __builtin_amdgcn_mfma_f32_16x16x32_bf16

static __device__ __forceinline__ u16 f2bf(float f){   // RTNE
  union { float f; unsigned int i; } v; v.f = f;
  return (u16)((v.i + 0x7FFFu + ((v.i >> 16) & 1u)) >> 16);
}
static __device__ __forceinline__ float bf2f(u16 u){
  union { unsigned int i; float f; } v; v.i = ((unsigned int)u) << 16; return v.f;
}
template<int CTRL>
static __device__ __forceinline__ float dppadd(float x){
  int m = __builtin_amdgcn_update_dpp(0, __builtin_bit_cast(int, x), CTRL, 0xF, 0xF, true);
  return x + __builtin_bit_cast(float, m);
}
// sum across the 16 lanes of each row (lane>>4 group); all lanes get the total
static __device__ __forceinline__ float rowsum16(float x){
  x = dppadd<0x121>(x);  // row_ror:1
  x = dppadd<0x122>(x);  // row_ror:2
  x = dppadd<0x124>(x);  // row_ror:4
  x = dppadd<0x128>(x);  // row_ror:8
  return x;
}

// ---- LDS layout (bytes) ----
constexpr int LDS_X   = 0;      // x_ext HI: 160 rows x 128B (bf16), chunks XOR-swizzled by (row&7)
constexpr int LDS_XLO = 20480;  // x_ext LO plane (same layout)
constexpr int LDS_KFT = 40960;  // kf_t : 16 planes x 256B  ([ch][128 tok] bf16, chunk-swizzled)
constexpr int LDS_VTT = 45056;  // v_t  : 16 planes x 256B
constexpr int LDS_VT2 = 49152;  // vt2  : 16 planes x 336B  ([21 rows][8 ws] bf16, rows 0..19 used)
constexpr int LDS_QFM = 54528;  // qf   : 8 waves x 512B    ([2 gb][16 tok][8 ch] bf16)
constexpr int LDS_KVB = 58624;  // kvB  : 16 x 80B          ([d][40 k] bf16, k>=16 are real zeros)
constexpr int LDS_KSP = 59904;  // ksum partials: 32 x 16 f32
constexpr int LDS_KVF = 61952;  // kv f32: 16 x 16
constexpr int LDS_KSH = 62976;  // ksum head: 16 f32
constexpr int LDS_TOT = 63040;

__global__ __launch_bounds__(512, 2)
void fla_fused(const float* __restrict__ xg,   const float* __restrict__ wqkv,
               const float* __restrict__ wgetv,const float* __restrict__ bgetv,
               const float* __restrict__ wdwc, const float* __restrict__ bdwc,
               const float* __restrict__ scalep, float* __restrict__ outg)
{
  __shared__ __attribute__((aligned(16))) char smem[LDS_TOT];
  u16*   xs  = (u16*)(smem + LDS_X);
  u16*   kft = (u16*)(smem + LDS_KFT);
  u16*   vtt = (u16*)(smem + LDS_VTT);
  u16*   vt2 = (u16*)(smem + LDS_VT2);
  u16*   qfm = (u16*)(smem + LDS_QFM);
  u16*   kvB = (u16*)(smem + LDS_KVB);
  float* ksp = (float*)(smem + LDS_KSP);
  float* kvf = (float*)(smem + LDS_KVF);
  float* ksh = (float*)(smem + LDS_KSH);

  const int bid  = blockIdx.x;
  const int h    = bid >> 7;        // head 0..3 (same-window heads share an XCD slot -> L2 reuse)
  const int wp   = bid & 127;       // window 0..127
  const int b    = wp >> 5;
  const int wcol = (wp & 31) * 8;

  const int tid  = threadIdx.x;
  const int wv   = tid >> 6;        // wave 0..7
  const int lane = tid & 63;
  const int g4   = lane >> 4;       // 16-lane group 0..3
  const int c15  = lane & 15;

  const size_t xbase = (size_t)b * (65536ull * 64ull);
  const int    swz   = (c15 & 7) << 4;

  // inverse softplus(scale) for the 4 channel groups this lane touches
  float isc[4];
#pragma unroll
  for (int nb = 0; nb < 4; ++nb){
    float p = scalep[nb*16 + c15];
    isc[nb] = 1.0f / logf(1.0f + expf(p));
  }

  // split an 8-float row slice into hi/lo bf16x8 MFMA fragments
  auto ldsplit = [&](const float* p, bf8v& hi, bf8v& lo){
    f32x4 u = *(const f32x4*)p;
    f32x4 w = *(const f32x4*)(p + 4);
#pragma unroll
    for (int j = 0; j < 4; ++j){
      u16 hb = f2bf(u[j]); hi[j]   = (short)hb; lo[j]   = (short)f2bf(u[j] - bf2f(hb));
      u16 hc = f2bf(w[j]); hi[4+j] = (short)hc; lo[4+j] = (short)f2bf(w[j] - bf2f(hc));
    }
  };

  // weight B-fragments (hi+lo) in registers: B[k=cin][n=cout] = w_qkv[cout][cin]
  bf8v WKh[4][2], WKl[4][2], WVh[2], WVl[2];
#pragma unroll
  for (int nb = 0; nb < 4; ++nb)
#pragma unroll
    for (int kt = 0; kt < 2; ++kt)
      ldsplit(wqkv + (size_t)(64 + nb*16 + c15)*64 + kt*32 + 8*g4, WKh[nb][kt], WKl[nb][kt]);
#pragma unroll
  for (int kt = 0; kt < 2; ++kt)
    ldsplit(wqkv + (size_t)(128 + h*16 + c15)*64 + kt*32 + 8*g4, WVh[kt], WVl[kt]);

  // stage nrows window-rows starting at window-row row0; OOB rows -> 0.
  // f32 global -> bf16 hi+lo planes in LDS.
  auto load_x = [&](int row0, int nrows){
    const int total = nrows * 64;          // 16B LDS chunks (8 channels each)
    for (int ci = tid; ci < total; ci += 512){
      const int te = ci >> 3;              // local ext-token index
      const int c8 = ci & 7;               // channel chunk
      const int hs = row0 + (te >> 3);
      bf8v vh = {0,0,0,0,0,0,0,0}, vl = {0,0,0,0,0,0,0,0};
      if (hs >= 0 && hs < 256){
        const size_t l = (size_t)hs * 256 + wcol + (te & 7);
        const float* p = xg + xbase + l*64 + c8*8;
        f32x4 u = *(const f32x4*)p;
        f32x4 w = *(const f32x4*)(p + 4);
#pragma unroll
        for (int j = 0; j < 4; ++j){
          u16 hb = f2bf(u[j]); vh[j]   = (short)hb; vl[j]   = (short)f2bf(u[j] - bf2f(hb));
          u16 hc = f2bf(w[j]); vh[4+j] = (short)hc; vl[4+j] = (short)f2bf(w[j] - bf2f(hc));
        }
      }
      const int off = te*128 + ((c8 ^ (te & 7)) << 4);
      *(bf8v*)((char*)xs + off)              = vh;
      *(bf8v*)((char*)xs + 20480 + off)      = vl;
    }
  };
  auto read_af = [&](int rowbase, int kt, int plane) -> bf8v {
    const int te = rowbase + c15;
    const int cc = kt*4 + g4;
    return *(const bf8v*)((char*)xs + plane*20480 + te*128 + ((cc ^ (te & 7)) << 4));
  };

  // focus on 4 N-tile D-frags (all 64 channels of 4 tokens); returns head-slice values
  auto focus = [&](const f32x4* dmat, float* fh){
    float s2[4] = {0,0,0,0}, s6[4] = {0,0,0,0};
    float h1[4], h2[4];
#pragma unroll
    for (int nb = 0; nb < 4; ++nb){
#pragma unroll
      for (int r = 0; r < 4; ++r){
        float t = fmaxf(dmat[nb][r], 0.0f) + 1e-6f;
        t *= isc[nb];
        float t2 = t * t;
        s2[r] += t2;
        s6[r] += t2 * t2 * t2;
        if (nb == h){ h1[r] = t; h2[r] = t2; }   // h is block-uniform -> no scratch
      }
    }
#pragma unroll
    for (int r = 0; r < 4; ++r){
      float a2 = rowsum16(s2[r]);
      float a6 = rowsum16(s6[r]);
      float f  = sqrtf(a2 / a6);               // n0 / ||t^3||
      fh[r] = h1[r] * h2[r] * f;               // t^3 * n0/n1
    }
  };

  // ================= Phase A: kv and ksum over the whole window =================
  f32x4 kvacc = {0,0,0,0};
  float ksump = 0.0f;

  for (int tile = 0; tile < 16; ++tile){
    __syncthreads();
    load_x(tile*16, 16);
    __syncthreads();

    bf8v a0  = read_af(16*wv, 0, 0);
    bf8v a1  = read_af(16*wv, 1, 0);
    bf8v a0l = read_af(16*wv, 0, 1);
    bf8v a1l = read_af(16*wv, 1, 1);
    f32x4 dk[4];
#pragma unroll
    for (int nb = 0; nb < 4; ++nb){
      f32x4 acc = {0,0,0,0};
      acc = MFMA(a0,  WKh[nb][0], acc, 0, 0, 0);
      acc = MFMA(a0,  WKl[nb][0], acc, 0, 0, 0);
      acc = MFMA(a0l, WKh[nb][0], acc, 0, 0, 0);
      acc = MFMA(a1,  WKh[nb][1], acc, 0, 0, 0);
      acc = MFMA(a1,  WKl[nb][1], acc, 0, 0, 0);
      acc = MFMA(a1l, WKh[nb][1], acc, 0, 0, 0);
      dk[nb] = acc;
    }
    f32x4 dv = {0,0,0,0};
    dv = MFMA(a0,  WVh[0], dv, 0, 0, 0);
    dv = MFMA(a0,  WVl[0], dv, 0, 0, 0);
    dv = MFMA(a0l, WVh[0], dv, 0, 0, 0);
    dv = MFMA(a1,  WVh[1], dv, 0, 0, 0);
    dv = MFMA(a1,  WVl[1], dv, 0, 0, 0);
    dv = MFMA(a1l, WVh[1], dv, 0, 0, 0);

    float kh[4];
    focus(dk, kh);
    ksump += (kh[0] + kh[1]) + (kh[2] + kh[3]);

    const int tl2 = (16*wv + 4*g4) * 2;      // token byte offset within plane
    bf4v pk, pv;
#pragma unroll
    for (int r = 0; r < 4; ++r){ pk[r] = (short)f2bf(kh[r]); pv[r] = (short)f2bf(dv[r]); }
    *(bf4v*)((char*)kft + c15*256 + (tl2 ^ swz)) = pk;
    *(bf4v*)((char*)vtt + c15*256 + (tl2 ^ swz)) = pv;

    __syncthreads();

    if (wv == 0){                            // kv += kf^T . v  (A[m=c][k=t], B[k=t][n=d])
#pragma unroll
      for (int k2 = 0; k2 < 4; ++k2){
        const int tb = k2*64 + g4*16;
        bf8v af = *(const bf8v*)((char*)kft + c15*256 + (tb ^ swz));
        bf8v bf = *(const bf8v*)((char*)vtt + c15*256 + (tb ^ swz));
        kvacc = MFMA(af, bf, kvacc, 0, 0, 0);
      }
    }
  }

  __syncthreads();
  ksp[(wv*4 + g4)*16 + c15] = ksump;
  if (wv == 0){
#pragma unroll
    for (int r = 0; r < 4; ++r) kvf[(4*g4 + r)*16 + c15] = kvacc[r];
  }
  __syncthreads();
  if (tid < 16){
    float s = 0.0f;
    for (int j = 0; j < 32; ++j) s += ksp[j*16 + tid];
    ksh[tid] = s;
  }
  {
    const int d = tid >> 5, k = tid & 31;    // 512 threads cover 16x32 exactly
    kvB[d*40 + k] = (k < 16) ? f2bf(kvf[k*16 + d]) : (u16)0;
  }
  __syncthreads();

  const bf8v  kvfrag = *(const bf8v*)((char*)kvB + c15*80 + g4*16);  // B[k][n=d], k>=16 zero
  const float ksr    = ksh[c15];

  // phase-B-only weights (loaded late to cut phase-A register pressure)
  bf8v WQh[4][2], WQl[4][2];
#pragma unroll
  for (int nb = 0; nb < 4; ++nb)
#pragma unroll
    for (int kt = 0; kt < 2; ++kt)
      ldsplit(wqkv + (size_t)(nb*16 + c15)*64 + kt*32 + 8*g4, WQh[nb][kt], WQl[nb][kt]);
  float wdw[25], wge[9];
#pragma unroll
  for (int i = 0; i < 25; ++i) wdw[i] = wdwc[c15*25 + i];
#pragma unroll
  for (int i = 0; i < 9;  ++i) wge[i] = wgetv[(h*16 + c15)*9 + i];
  const float bdw = bdwc[c15];
  const float bge = bgetv[h*16 + c15];

  // ================= Phase B: q focus, attention out, convs, store =================
  for (int tile = 0; tile < 16; ++tile){
    __syncthreads();
    load_x(tile*16 - 2, 20);                 // 20 rows incl. +-2 halo; OOB rows are zeros
    __syncthreads();

    // v over extended rows (zero x rows -> zero v == conv zero padding, v has no bias)
    for (int mt = wv; mt < 10; mt += 8){
      bf8v va0  = read_af(16*mt, 0, 0);
      bf8v va1  = read_af(16*mt, 1, 0);
      bf8v va0l = read_af(16*mt, 0, 1);
      bf8v va1l = read_af(16*mt, 1, 1);
      f32x4 dv = {0,0,0,0};
      dv = MFMA(va0,  WVh[0], dv, 0, 0, 0);
      dv = MFMA(va0,  WVl[0], dv, 0, 0, 0);
      dv = MFMA(va0l, WVh[0], dv, 0, 0, 0);
      dv = MFMA(va1,  WVh[1], dv, 0, 0, 0);
      dv = MFMA(va1,  WVl[1], dv, 0, 0, 0);
      dv = MFMA(va1l, WVh[1], dv, 0, 0, 0);
      const int te = 16*mt + 4*g4;           // ext token base (4 consecutive ws)
      bf4v pv;
#pragma unroll
      for (int r = 0; r < 4; ++r) pv[r] = (short)f2bf(dv[r]);
      *(bf4v*)((char*)vt2 + c15*336 + (te >> 3)*16 + (te & 7)*2) = pv;
    }

    // q on center rows: ext tokens 16 + 16*wv .. +15
    bf8v a0  = read_af(16 + 16*wv, 0, 0);
    bf8v a1  = read_af(16 + 16*wv, 1, 0);
    bf8v a0l = read_af(16 + 16*wv, 0, 1);
    bf8v a1l = read_af(16 + 16*wv, 1, 1);
    f32x4 dq[4];
#pragma unroll
    for (int nb = 0; nb < 4; ++nb){
      f32x4 acc = {0,0,0,0};
      acc = MFMA(a0,  WQh[nb][0], acc, 0, 0, 0);
      acc = MFMA(a0,  WQl[nb][0], acc, 0, 0, 0);
      acc = MFMA(a0l, WQh[nb][0], acc, 0, 0, 0);
      acc = MFMA(a1,  WQh[nb][1], acc, 0, 0, 0);
      acc = MFMA(a1,  WQl[nb][1], acc, 0, 0, 0);
      acc = MFMA(a1l, WQh[nb][1], acc, 0, 0, 0);
      dq[nb] = acc;
    }
    float qh[4];
    focus(dq, qh);

    float z[4];
#pragma unroll
    for (int r = 0; r < 4; ++r){
      float dot = rowsum16(qh[r] * ksr);     // sum over the 16 head channels
      z[r] = 1.0f / (dot + 1e-6f);
    }

    {                                        // transpose qf into [tok][ch] for the A-frag
      const int base = wv*512 + (c15 >> 3)*256 + (c15 & 7)*2;
#pragma unroll
      for (int r = 0; r < 4; ++r)
        *(u16*)((char*)qfm + base + (4*g4 + r)*16) = f2bf(qh[r]);
    }

    __syncthreads();                         // vt2 (cross-wave) + qfm ready

    bf8v aq = *(const bf8v*)((char*)qfm + wv*512 + (g4 & 1)*256 + c15*16);
    f32x4 dat = {0,0,0,0};
    dat = MFMA(aq, kvfrag, dat, 0, 0, 0);    // attn numerator, K padded with real zeros

    // convs: lane owns channel c15, 4 consecutive-ws tokens in one image row
    const int  hsl = 2*wv + (g4 >> 1);       // vt2 row of (center hs - 2)
    const bool w0  = ((g4 & 1) == 0);        // ws base 0 or 4
    float swv[5][8];                          // shifted window: col (wsbase-2+i)
#pragma unroll
    for (int dy = 0; dy < 5; ++dy){
      bf8v rv = *(const bf8v*)((char*)vt2 + c15*336 + (hsl + dy)*16);
      float rf[8];
#pragma unroll
      for (int i = 0; i < 8; ++i) rf[i] = bf2f((u16)rv[i]);
      swv[dy][0] = w0 ? 0.0f : rf[2];
      swv[dy][1] = w0 ? 0.0f : rf[3];
      swv[dy][2] = w0 ? rf[0] : rf[4];
      swv[dy][3] = w0 ? rf[1] : rf[5];
      swv[dy][4] = w0 ? rf[2] : rf[6];
      swv[dy][5] = w0 ? rf[3] : rf[7];
      swv[dy][6] = w0 ? rf[4] : 0.0f;
      swv[dy][7] = w0 ? rf[5] : 0.0f;
    }

#pragma unroll
    for (int r = 0; r < 4; ++r){
      float accf = bdw;                      // 5x5 depthwise (fmap)
#pragma unroll
      for (int dy = 0; dy < 5; ++dy)
#pragma unroll
        for (int dx = 0; dx < 5; ++dx)
          accf += swv[dy][r + dx] * wdw[dy*5 + dx];
      float accl = bge;                      // 3x3 depthwise (lepe)
#pragma unroll
      for (int ky = 0; ky < 3; ++ky)
#pragma unroll
        for (int kx = 0; kx < 3; ++kx)
          accl += swv[1 + ky][r + 1 + kx] * wge[ky*3 + kx];

      const int    twin = tile*128 + 16*wv + 4*g4 + r;          // window token
      const size_t l    = (size_t)(twin >> 3) * 256 + wcol + (twin & 7);
      outg[xbase + l*64 + h*16 + c15] = dat[r] * z[r] + accf + accl;
    }
  }
}

extern "C" void kernel_launch(void* const* d_in, const int* in_sizes, int n_in,
                              void* d_out, int out_size, void* d_ws, size_t ws_size,
                              hipStream_t stream)
{
  (void)in_sizes; (void)n_in; (void)d_ws; (void)ws_size; (void)out_size;
  fla_fused<<<dim3(512), dim3(512), 0, stream>>>(
      (const float*)d_in[0], (const float*)d_in[1], (const float*)d_in[2],
      (const float*)d_in[3], (const float*)d_in[4], (const float*)d_in[5],
      (const float*)d_in[6], (float*)d_out);
}

// Round 5
// 185.214 us; speedup vs baseline: 1.2891x; 1.2891x over previous
//
#include <hip/hip_runtime.h>

// FocusedLinearAttention — MI355X gfx950. f32 in/out (bf16-rounded values;
// threshold 2% of max|ref|). Round-5: K1 computes per-(window,quarter) partial
// kv (all 4 heads) + ksum (all 64 ch) into d_ws, deduplicating phase A's x4
// head redundancy. K2 = the validated round-3 mono kernel with phase A
// replaced by a ws-reduction prologue; its phase-B loop is verbatim round-3.
//
// MFMA layout (v_mfma_f32_16x16x32_bf16), HW-verified via round-3 pass:
//   A: lane l elem j -> A[m=l&15][k=8*(l>>4)+j]
//   B: lane l elem j -> B[k=8*(l>>4)+j][n=l&15]
//   D: lane l reg  r -> D[m=4*(l>>4)+r][n=l&15]

typedef float f32x4 __attribute__((ext_vector_type(4)));
typedef short bf8v  __attribute__((ext_vector_type(8)));
typedef short bf4v  __attribute__((ext_vector_type(4)));
typedef unsigned short u16;

#define MFMA __builtin_amdgcn_mfma_f32_16x16x32_bf16

static __device__ __forceinline__ u16 f2bf(float f){   // RTNE (validated r3)
  union { float f; unsigned int i; } v; v.f = f;
  return (u16)((v.i + 0x7FFFu + ((v.i >> 16) & 1u)) >> 16);
}
static __device__ __forceinline__ float bf2f(u16 u){
  union { unsigned int i; float f; } v; v.i = ((unsigned int)u) << 16; return v.f;
}
template<int CTRL>
static __device__ __forceinline__ float dppadd(float x){
  int m = __builtin_amdgcn_update_dpp(0, __builtin_bit_cast(int, x), CTRL, 0xF, 0xF, true);
  return x + __builtin_bit_cast(float, m);
}
static __device__ __forceinline__ float rowsum16(float x){
  x = dppadd<0x121>(x); x = dppadd<0x122>(x); x = dppadd<0x124>(x); x = dppadd<0x128>(x);
  return x;
}

// ---- workspace layout (float offsets) ----
constexpr int    WS_KV = 0;            // [128 wp][4 qt][4 h][16 kch][16 vch] f32
constexpr int    WS_KS = 524288;       // [128 wp][4 qt][64 ch] f32
constexpr size_t WS_NEED_BYTES = (524288ull + 32768ull) * 4ull;   // 2,228,224

// ======================= K1: partial kv + ksum per (window, quarter) =======================
constexpr int A_XSH = 0;       // 128 tok x 128B bf16 hi (chunk-xor swizzle); ksp aliases after use
constexpr int A_XSL = 16384;   // lo plane
constexpr int A_KFT = 32768;   // [64 ch][128 tok] bf16, 256B rows, chunk-swizzled
constexpr int A_VTT = 49152;   // same for v
constexpr int A_TOT = 65536;

// focus for all 4 channel groups of 4 tokens (lane = ch nb*16+c15, tok 4*g4+r)
static __device__ __forceinline__ void focus16(const f32x4 d[4], const float isc[4], float kh[4][4]){
  float s2[4] = {0,0,0,0}, s6[4] = {0,0,0,0};
#pragma unroll
  for (int nb = 0; nb < 4; ++nb)
#pragma unroll
    for (int r = 0; r < 4; ++r){
      float t = fmaxf(d[nb][r], 0.0f) + 1e-6f;
      t *= isc[nb];
      const float t2 = t * t;
      s2[r] += t2; s6[r] += t2 * t2 * t2;
      kh[nb][r] = t;
    }
#pragma unroll
  for (int r = 0; r < 4; ++r){
    const float f = sqrtf(rowsum16(s2[r]) / rowsum16(s6[r]));
#pragma unroll
    for (int nb = 0; nb < 4; ++nb){
      const float t = kh[nb][r];
      kh[nb][r] = t * t * t * f;
    }
  }
}

__global__ __launch_bounds__(512, 2)
void fla_k1(const float* __restrict__ xg, const float* __restrict__ wqkv,
            const float* __restrict__ scalep, float* __restrict__ ws)
{
  __shared__ __attribute__((aligned(16))) char smem[A_TOT];
  const int bid = blockIdx.x;
  const int qt = bid >> 7, wp = bid & 127;
  const int b = wp >> 5, wcol = (wp & 31) * 8;
  const int tid = threadIdx.x, wv = tid >> 6, lane = tid & 63;
  const int g4 = lane >> 4, c15 = lane & 15;
  const size_t xbase = (size_t)b * (65536ull * 64ull);
  const int swz = (c15 & 7) << 4;

  auto ldsplit = [&](const float* p, bf8v& hi, bf8v& lo){
    f32x4 u = *(const f32x4*)p;
    f32x4 w = *(const f32x4*)(p + 4);
#pragma unroll
    for (int j = 0; j < 4; ++j){
      u16 hb = f2bf(u[j]); hi[j]   = (short)hb; lo[j]   = (short)f2bf(u[j] - bf2f(hb));
      u16 hc = f2bf(w[j]); hi[4+j] = (short)hc; lo[4+j] = (short)f2bf(w[j] - bf2f(hc));
    }
  };
  auto loadA = [&](int t){
    const int row0 = qt*64 + t*16;                 // always in [0,256)
    for (int ci = tid; ci < 1024; ci += 512){
      const int te = ci >> 3, c8 = ci & 7;
      const float* p = xg + xbase + ((size_t)(row0 + (te >> 3)) * 256 + wcol + (te & 7)) * 64 + c8 * 8;
      bf8v vh, vl;
      f32x4 u = *(const f32x4*)p, w = *(const f32x4*)(p + 4);
#pragma unroll
      for (int j = 0; j < 4; ++j){
        u16 hb = f2bf(u[j]); vh[j]   = (short)hb; vl[j]   = (short)f2bf(u[j] - bf2f(hb));
        u16 hc = f2bf(w[j]); vh[4+j] = (short)hc; vl[4+j] = (short)f2bf(w[j] - bf2f(hc));
      }
      const int off = te * 128 + ((c8 ^ (te & 7)) << 4);
      *(bf8v*)(smem + A_XSH + off) = vh;
      *(bf8v*)(smem + A_XSL + off) = vl;
    }
  };
  auto rdA = [&](int plane, int tokbase, int cc) -> bf8v {
    const int te = tokbase + c15;
    return *(const bf8v*)(smem + plane + te * 128 + ((cc ^ (te & 7)) << 4));
  };

  if (wv < 4){
    // -------- k role: focused k (all 64 ch) -> kft, ksum; kv MFMA for head wv --------
    float isc[4];
#pragma unroll
    for (int nb = 0; nb < 4; ++nb) isc[nb] = 1.0f / logf(1.0f + expf(scalep[nb*16 + c15]));
    bf8v WKh[4][2], WKl[4][2];
#pragma unroll
    for (int nb = 0; nb < 4; ++nb)
#pragma unroll
      for (int kt = 0; kt < 2; ++kt)
        ldsplit(wqkv + (size_t)(64 + nb*16 + c15)*64 + kt*32 + 8*g4, WKh[nb][kt], WKl[nb][kt]);

    float ksA[4] = {0,0,0,0};
    f32x4 kvacc = {0,0,0,0};
    for (int t = 0; t < 4; ++t){
      __syncthreads();
      loadA(t);
      __syncthreads();
#pragma unroll
      for (int s = 0; s < 2; ++s){
        const int tg = wv*2 + s;                   // token group 0..7
        bf8v a0  = rdA(A_XSH, tg*16, g4),  a1  = rdA(A_XSH, tg*16, 4 + g4);
        bf8v a0l = rdA(A_XSL, tg*16, g4),  a1l = rdA(A_XSL, tg*16, 4 + g4);
        f32x4 dk[4];
#pragma unroll
        for (int nb = 0; nb < 4; ++nb){
          f32x4 acc = {0,0,0,0};
          acc = MFMA(a0,  WKh[nb][0], acc, 0,0,0);
          acc = MFMA(a0,  WKl[nb][0], acc, 0,0,0);
          acc = MFMA(a0l, WKh[nb][0], acc, 0,0,0);
          acc = MFMA(a1,  WKh[nb][1], acc, 0,0,0);
          acc = MFMA(a1,  WKl[nb][1], acc, 0,0,0);
          acc = MFMA(a1l, WKh[nb][1], acc, 0,0,0);
          dk[nb] = acc;
        }
        float kh[4][4];
        focus16(dk, isc, kh);
        const int tb2 = (tg*16 + 4*g4) * 2;
#pragma unroll
        for (int nb = 0; nb < 4; ++nb){
          ksA[nb] += (kh[nb][0] + kh[nb][1]) + (kh[nb][2] + kh[nb][3]);
          bf4v pk;
#pragma unroll
          for (int r = 0; r < 4; ++r) pk[r] = (short)f2bf(kh[nb][r]);
          *(bf4v*)(smem + A_KFT + (nb*16 + c15)*256 + (tb2 ^ swz)) = pk;
        }
      }
      __syncthreads();
#pragma unroll
      for (int k2 = 0; k2 < 4; ++k2){              // kv += kf^T . v for head wv
        const int tb = k2*64 + g4*16;
        bf8v af = *(const bf8v*)(smem + A_KFT + (wv*16 + c15)*256 + (tb ^ swz));
        bf8v bv = *(const bf8v*)(smem + A_VTT + (wv*16 + c15)*256 + (tb ^ swz));
        kvacc = MFMA(af, bv, kvacc, 0,0,0);
      }
    }
    __syncthreads();                               // epi (matched in v role)
    float* ksp = (float*)smem;                     // reuse XSH region
#pragma unroll
    for (int nb = 0; nb < 4; ++nb) ksp[(wv*4 + g4)*64 + nb*16 + c15] = ksA[nb];
    float* kvp = ws + WS_KV + ((wp*4 + qt)*4 + wv) * 256;
#pragma unroll
    for (int r = 0; r < 4; ++r) kvp[(4*g4 + r)*16 + c15] = kvacc[r];
  } else {
    // -------- v role: v (all 64 ch, hi+lo split like mono) -> vtt --------
    bf8v WVh[4][2], WVl[4][2];
#pragma unroll
    for (int nb = 0; nb < 4; ++nb)
#pragma unroll
      for (int kt = 0; kt < 2; ++kt)
        ldsplit(wqkv + (size_t)(128 + nb*16 + c15)*64 + kt*32 + 8*g4, WVh[nb][kt], WVl[nb][kt]);

    for (int t = 0; t < 4; ++t){
      __syncthreads();
      loadA(t);
      __syncthreads();
#pragma unroll
      for (int s = 0; s < 2; ++s){
        const int tg = (wv - 4)*2 + s;
        bf8v a0  = rdA(A_XSH, tg*16, g4),  a1  = rdA(A_XSH, tg*16, 4 + g4);
        bf8v a0l = rdA(A_XSL, tg*16, g4),  a1l = rdA(A_XSL, tg*16, 4 + g4);
        const int tb2 = (tg*16 + 4*g4) * 2;
#pragma unroll
        for (int nb = 0; nb < 4; ++nb){
          f32x4 acc = {0,0,0,0};
          acc = MFMA(a0,  WVh[nb][0], acc, 0,0,0);
          acc = MFMA(a0,  WVl[nb][0], acc, 0,0,0);
          acc = MFMA(a0l, WVh[nb][0], acc, 0,0,0);
          acc = MFMA(a1,  WVh[nb][1], acc, 0,0,0);
          acc = MFMA(a1,  WVl[nb][1], acc, 0,0,0);
          acc = MFMA(a1l, WVh[nb][1], acc, 0,0,0);
          bf4v pv;
#pragma unroll
          for (int r = 0; r < 4; ++r) pv[r] = (short)f2bf(acc[r]);
          *(bf4v*)(smem + A_VTT + (nb*16 + c15)*256 + (tb2 ^ swz)) = pv;
        }
      }
      __syncthreads();                             // k waves do kv here
    }
    __syncthreads();                               // epi
  }
  __syncthreads();
  if (tid < 64){
    const float* ksp = (const float*)smem;
    float s = 0.0f;
    for (int j = 0; j < 16; ++j) s += ksp[j*64 + tid];
    ws[WS_KS + (wp*4 + qt)*64 + tid] = s;
  }
}

// ======================= K2: round-3 mono with phase A replaced by ws prologue =======================
constexpr int LDS_X   = 0;      // x_ext HI: 160 rows x 128B; LO at +20480
constexpr int LDS_VT2 = 49152;  // [16 ch][21 rows][8 ws] bf16, 336B rows
constexpr int LDS_QFM = 54528;  // [8 waves][2 gb][16 tok][8 ch] bf16
constexpr int LDS_KVB = 58624;  // [16 d][40 k] bf16 (k>=16 zero)
constexpr int LDS_KSH = 62976;  // ksum head: 16 f32
constexpr int LDS_TOT = 63040;

__global__ __launch_bounds__(512, 2)
void fla_k2(const float* __restrict__ xg,   const float* __restrict__ wqkv,
            const float* __restrict__ wgetv,const float* __restrict__ bgetv,
            const float* __restrict__ wdwc, const float* __restrict__ bdwc,
            const float* __restrict__ scalep, const float* __restrict__ ws,
            float* __restrict__ outg)
{
  __shared__ __attribute__((aligned(16))) char smem[LDS_TOT];
  u16*   xs  = (u16*)(smem + LDS_X);
  u16*   vt2 = (u16*)(smem + LDS_VT2);
  u16*   qfm = (u16*)(smem + LDS_QFM);
  u16*   kvB = (u16*)(smem + LDS_KVB);
  float* ksh = (float*)(smem + LDS_KSH);

  const int bid  = blockIdx.x;
  const int h    = bid >> 7;
  const int wp   = bid & 127;
  const int b    = wp >> 5;
  const int wcol = (wp & 31) * 8;
  const int tid  = threadIdx.x;
  const int wv   = tid >> 6;
  const int lane = tid & 63;
  const int g4   = lane >> 4;
  const int c15  = lane & 15;
  const size_t xbase = (size_t)b * (65536ull * 64ull);

  float isc[4];
#pragma unroll
  for (int nb = 0; nb < 4; ++nb){
    float p = scalep[nb*16 + c15];
    isc[nb] = 1.0f / logf(1.0f + expf(p));
  }
  auto ldsplit = [&](const float* p, bf8v& hi, bf8v& lo){
    f32x4 u = *(const f32x4*)p;
    f32x4 w = *(const f32x4*)(p + 4);
#pragma unroll
    for (int j = 0; j < 4; ++j){
      u16 hb = f2bf(u[j]); hi[j]   = (short)hb; lo[j]   = (short)f2bf(u[j] - bf2f(hb));
      u16 hc = f2bf(w[j]); hi[4+j] = (short)hc; lo[4+j] = (short)f2bf(w[j] - bf2f(hc));
    }
  };
  bf8v WVh[2], WVl[2];
#pragma unroll
  for (int kt = 0; kt < 2; ++kt)
    ldsplit(wqkv + (size_t)(128 + h*16 + c15)*64 + kt*32 + 8*g4, WVh[kt], WVl[kt]);

  auto load_x = [&](int row0, int nrows){
    const int total = nrows * 64;
    for (int ci = tid; ci < total; ci += 512){
      const int te = ci >> 3;
      const int c8 = ci & 7;
      const int hs = row0 + (te >> 3);
      bf8v vh = {0,0,0,0,0,0,0,0}, vl = {0,0,0,0,0,0,0,0};
      if (hs >= 0 && hs < 256){
        const size_t l = (size_t)hs * 256 + wcol + (te & 7);
        const float* p = xg + xbase + l*64 + c8*8;
        f32x4 u = *(const f32x4*)p;
        f32x4 w = *(const f32x4*)(p + 4);
#pragma unroll
        for (int j = 0; j < 4; ++j){
          u16 hb = f2bf(u[j]); vh[j]   = (short)hb; vl[j]   = (short)f2bf(u[j] - bf2f(hb));
          u16 hc = f2bf(w[j]); vh[4+j] = (short)hc; vl[4+j] = (short)f2bf(w[j] - bf2f(hc));
        }
      }
      const int off = te*128 + ((c8 ^ (te & 7)) << 4);
      *(bf8v*)((char*)xs + off)         = vh;
      *(bf8v*)((char*)xs + 20480 + off) = vl;
    }
  };
  auto read_af = [&](int rowbase, int kt, int plane) -> bf8v {
    const int te = rowbase + c15;
    const int cc = kt*4 + g4;
    return *(const bf8v*)((char*)xs + plane*20480 + te*128 + ((cc ^ (te & 7)) << 4));
  };
  auto focus = [&](const f32x4* dmat, float* fh){
    float s2[4] = {0,0,0,0}, s6[4] = {0,0,0,0};
    float h1[4], h2[4];
#pragma unroll
    for (int nb = 0; nb < 4; ++nb){
#pragma unroll
      for (int r = 0; r < 4; ++r){
        float t = fmaxf(dmat[nb][r], 0.0f) + 1e-6f;
        t *= isc[nb];
        float t2 = t * t;
        s2[r] += t2;
        s6[r] += t2 * t2 * t2;
        if (nb == h){ h1[r] = t; h2[r] = t2; }
      }
    }
#pragma unroll
    for (int r = 0; r < 4; ++r){
      float a2 = rowsum16(s2[r]);
      float a6 = rowsum16(s6[r]);
      float f  = sqrtf(a2 / a6);
      fh[r] = h1[r] * h2[r] * f;
    }
  };

  // ---- prologue: reduce quarter partials from ws into ksh / kvB ----
  if (tid < 16){
    float s = 0.0f;
#pragma unroll
    for (int q2 = 0; q2 < 4; ++q2) s += ws[WS_KS + (wp*4 + q2)*64 + h*16 + tid];
    ksh[tid] = s;
  }
  {
    const int d = tid >> 5, k = tid & 31;          // 512 threads cover 16x32
    float s = 0.0f;
    if (k < 16){
#pragma unroll
      for (int q2 = 0; q2 < 4; ++q2) s += ws[WS_KV + ((wp*4 + q2)*4 + h)*256 + k*16 + d];
    }
    kvB[d*40 + k] = (k < 16) ? f2bf(s) : (u16)0;
  }
  __syncthreads();

  const bf8v  kvfrag = *(const bf8v*)((char*)kvB + c15*80 + g4*16);
  const float ksr    = ksh[c15];

  bf8v WQh[4][2], WQl[4][2];
#pragma unroll
  for (int nb = 0; nb < 4; ++nb)
#pragma unroll
    for (int kt = 0; kt < 2; ++kt)
      ldsplit(wqkv + (size_t)(nb*16 + c15)*64 + kt*32 + 8*g4, WQh[nb][kt], WQl[nb][kt]);
  float wdw[25], wge[9];
#pragma unroll
  for (int i = 0; i < 25; ++i) wdw[i] = wdwc[c15*25 + i];
#pragma unroll
  for (int i = 0; i < 9;  ++i) wge[i] = wgetv[(h*16 + c15)*9 + i];
  const float bdw = bdwc[c15];
  const float bge = bgetv[h*16 + c15];

  // ---- phase B: verbatim round-3 ----
  for (int tile = 0; tile < 16; ++tile){
    __syncthreads();
    load_x(tile*16 - 2, 20);
    __syncthreads();

    for (int mt = wv; mt < 10; mt += 8){
      bf8v va0  = read_af(16*mt, 0, 0);
      bf8v va1  = read_af(16*mt, 1, 0);
      bf8v va0l = read_af(16*mt, 0, 1);
      bf8v va1l = read_af(16*mt, 1, 1);
      f32x4 dv = {0,0,0,0};
      dv = MFMA(va0,  WVh[0], dv, 0, 0, 0);
      dv = MFMA(va0,  WVl[0], dv, 0, 0, 0);
      dv = MFMA(va0l, WVh[0], dv, 0, 0, 0);
      dv = MFMA(va1,  WVh[1], dv, 0, 0, 0);
      dv = MFMA(va1,  WVl[1], dv, 0, 0, 0);
      dv = MFMA(va1l, WVh[1], dv, 0, 0, 0);
      const int te = 16*mt + 4*g4;
      bf4v pv;
#pragma unroll
      for (int r = 0; r < 4; ++r) pv[r] = (short)f2bf(dv[r]);
      *(bf4v*)((char*)vt2 + c15*336 + (te >> 3)*16 + (te & 7)*2) = pv;
    }

    bf8v a0  = read_af(16 + 16*wv, 0, 0);
    bf8v a1  = read_af(16 + 16*wv, 1, 0);
    bf8v a0l = read_af(16 + 16*wv, 0, 1);
    bf8v a1l = read_af(16 + 16*wv, 1, 1);
    f32x4 dq[4];
#pragma unroll
    for (int nb = 0; nb < 4; ++nb){
      f32x4 acc = {0,0,0,0};
      acc = MFMA(a0,  WQh[nb][0], acc, 0, 0, 0);
      acc = MFMA(a0,  WQl[nb][0], acc, 0, 0, 0);
      acc = MFMA(a0l, WQh[nb][0], acc, 0, 0, 0);
      acc = MFMA(a1,  WQh[nb][1], acc, 0, 0, 0);
      acc = MFMA(a1,  WQl[nb][1], acc, 0, 0, 0);
      acc = MFMA(a1l, WQh[nb][1], acc, 0, 0, 0);
      dq[nb] = acc;
    }
    float qh[4];
    focus(dq, qh);
    float z[4];
#pragma unroll
    for (int r = 0; r < 4; ++r){
      float dot = rowsum16(qh[r] * ksr);
      z[r] = 1.0f / (dot + 1e-6f);
    }
    {
      const int base = wv*512 + (c15 >> 3)*256 + (c15 & 7)*2;
#pragma unroll
      for (int r = 0; r < 4; ++r)
        *(u16*)((char*)qfm + base + (4*g4 + r)*16) = f2bf(qh[r]);
    }

    __syncthreads();

    bf8v aq = *(const bf8v*)((char*)qfm + wv*512 + (g4 & 1)*256 + c15*16);
    f32x4 dat = {0,0,0,0};
    dat = MFMA(aq, kvfrag, dat, 0, 0, 0);

    const int  hsl = 2*wv + (g4 >> 1);
    const bool w0  = ((g4 & 1) == 0);
    float swv[5][8];
#pragma unroll
    for (int dy = 0; dy < 5; ++dy){
      bf8v rv = *(const bf8v*)((char*)vt2 + c15*336 + (hsl + dy)*16);
      float rf[8];
#pragma unroll
      for (int i = 0; i < 8; ++i) rf[i] = bf2f((u16)rv[i]);
      swv[dy][0] = w0 ? 0.0f : rf[2];
      swv[dy][1] = w0 ? 0.0f : rf[3];
      swv[dy][2] = w0 ? rf[0] : rf[4];
      swv[dy][3] = w0 ? rf[1] : rf[5];
      swv[dy][4] = w0 ? rf[2] : rf[6];
      swv[dy][5] = w0 ? rf[3] : rf[7];
      swv[dy][6] = w0 ? rf[4] : 0.0f;
      swv[dy][7] = w0 ? rf[5] : 0.0f;
    }

#pragma unroll
    for (int r = 0; r < 4; ++r){
      float accf = bdw;
#pragma unroll
      for (int dy = 0; dy < 5; ++dy)
#pragma unroll
        for (int dx = 0; dx < 5; ++dx)
          accf += swv[dy][r + dx] * wdw[dy*5 + dx];
      float accl = bge;
#pragma unroll
      for (int ky = 0; ky < 3; ++ky)
#pragma unroll
        for (int kx = 0; kx < 3; ++kx)
          accl += swv[1 + ky][r + 1 + kx] * wge[ky*3 + kx];
      const int    twin = tile*128 + 16*wv + 4*g4 + r;
      const size_t l    = (size_t)(twin >> 3) * 256 + wcol + (twin & 7);
      outg[xbase + l*64 + h*16 + c15] = dat[r] * z[r] + accf + accl;
    }
  }
}

// ======================= round-3 mono kernel (fallback if ws too small) =======================
constexpr int M_KFT = 40960;
constexpr int M_VTT = 45056;
constexpr int M_KSP = 59904;
constexpr int M_KVF = 61952;

__global__ __launch_bounds__(512, 2)
void fla_fused(const float* __restrict__ xg,   const float* __restrict__ wqkv,
               const float* __restrict__ wgetv,const float* __restrict__ bgetv,
               const float* __restrict__ wdwc, const float* __restrict__ bdwc,
               const float* __restrict__ scalep, float* __restrict__ outg)
{
  __shared__ __attribute__((aligned(16))) char smem[LDS_TOT];
  u16*   xs  = (u16*)(smem + LDS_X);
  u16*   kft = (u16*)(smem + M_KFT);
  u16*   vtt = (u16*)(smem + M_VTT);
  u16*   vt2 = (u16*)(smem + LDS_VT2);
  u16*   qfm = (u16*)(smem + LDS_QFM);
  u16*   kvB = (u16*)(smem + LDS_KVB);
  float* ksp = (float*)(smem + M_KSP);
  float* kvf = (float*)(smem + M_KVF);
  float* ksh = (float*)(smem + LDS_KSH);

  const int bid  = blockIdx.x;
  const int h    = bid >> 7;
  const int wp   = bid & 127;
  const int b    = wp >> 5;
  const int wcol = (wp & 31) * 8;
  const int tid  = threadIdx.x;
  const int wv   = tid >> 6;
  const int lane = tid & 63;
  const int g4   = lane >> 4;
  const int c15  = lane & 15;
  const size_t xbase = (size_t)b * (65536ull * 64ull);
  const int    swz   = (c15 & 7) << 4;

  float isc[4];
#pragma unroll
  for (int nb = 0; nb < 4; ++nb){
    float p = scalep[nb*16 + c15];
    isc[nb] = 1.0f / logf(1.0f + expf(p));
  }
  auto ldsplit = [&](const float* p, bf8v& hi, bf8v& lo){
    f32x4 u = *(const f32x4*)p;
    f32x4 w = *(const f32x4*)(p + 4);
#pragma unroll
    for (int j = 0; j < 4; ++j){
      u16 hb = f2bf(u[j]); hi[j]   = (short)hb; lo[j]   = (short)f2bf(u[j] - bf2f(hb));
      u16 hc = f2bf(w[j]); hi[4+j] = (short)hc; lo[4+j] = (short)f2bf(w[j] - bf2f(hc));
    }
  };
  bf8v WKh[4][2], WKl[4][2], WVh[2], WVl[2];
#pragma unroll
  for (int nb = 0; nb < 4; ++nb)
#pragma unroll
    for (int kt = 0; kt < 2; ++kt)
      ldsplit(wqkv + (size_t)(64 + nb*16 + c15)*64 + kt*32 + 8*g4, WKh[nb][kt], WKl[nb][kt]);
#pragma unroll
  for (int kt = 0; kt < 2; ++kt)
    ldsplit(wqkv + (size_t)(128 + h*16 + c15)*64 + kt*32 + 8*g4, WVh[kt], WVl[kt]);

  auto load_x = [&](int row0, int nrows){
    const int total = nrows * 64;
    for (int ci = tid; ci < total; ci += 512){
      const int te = ci >> 3;
      const int c8 = ci & 7;
      const int hs = row0 + (te >> 3);
      bf8v vh = {0,0,0,0,0,0,0,0}, vl = {0,0,0,0,0,0,0,0};
      if (hs >= 0 && hs < 256){
        const size_t l = (size_t)hs * 256 + wcol + (te & 7);
        const float* p = xg + xbase + l*64 + c8*8;
        f32x4 u = *(const f32x4*)p;
        f32x4 w = *(const f32x4*)(p + 4);
#pragma unroll
        for (int j = 0; j < 4; ++j){
          u16 hb = f2bf(u[j]); vh[j]   = (short)hb; vl[j]   = (short)f2bf(u[j] - bf2f(hb));
          u16 hc = f2bf(w[j]); vh[4+j] = (short)hc; vl[4+j] = (short)f2bf(w[j] - bf2f(hc));
        }
      }
      const int off = te*128 + ((c8 ^ (te & 7)) << 4);
      *(bf8v*)((char*)xs + off)         = vh;
      *(bf8v*)((char*)xs + 20480 + off) = vl;
    }
  };
  auto read_af = [&](int rowbase, int kt, int plane) -> bf8v {
    const int te = rowbase + c15;
    const int cc = kt*4 + g4;
    return *(const bf8v*)((char*)xs + plane*20480 + te*128 + ((cc ^ (te & 7)) << 4));
  };
  auto focus = [&](const f32x4* dmat, float* fh){
    float s2[4] = {0,0,0,0}, s6[4] = {0,0,0,0};
    float h1[4], h2[4];
#pragma unroll
    for (int nb = 0; nb < 4; ++nb){
#pragma unroll
      for (int r = 0; r < 4; ++r){
        float t = fmaxf(dmat[nb][r], 0.0f) + 1e-6f;
        t *= isc[nb];
        float t2 = t * t;
        s2[r] += t2;
        s6[r] += t2 * t2 * t2;
        if (nb == h){ h1[r] = t; h2[r] = t2; }
      }
    }
#pragma unroll
    for (int r = 0; r < 4; ++r){
      float a2 = rowsum16(s2[r]);
      float a6 = rowsum16(s6[r]);
      float f  = sqrtf(a2 / a6);
      fh[r] = h1[r] * h2[r] * f;
    }
  };

  f32x4 kvacc = {0,0,0,0};
  float ksump = 0.0f;
  for (int tile = 0; tile < 16; ++tile){
    __syncthreads();
    load_x(tile*16, 16);
    __syncthreads();
    bf8v a0  = read_af(16*wv, 0, 0);
    bf8v a1  = read_af(16*wv, 1, 0);
    bf8v a0l = read_af(16*wv, 0, 1);
    bf8v a1l = read_af(16*wv, 1, 1);
    f32x4 dk[4];
#pragma unroll
    for (int nb = 0; nb < 4; ++nb){
      f32x4 acc = {0,0,0,0};
      acc = MFMA(a0,  WKh[nb][0], acc, 0, 0, 0);
      acc = MFMA(a0,  WKl[nb][0], acc, 0, 0, 0);
      acc = MFMA(a0l, WKh[nb][0], acc, 0, 0, 0);
      acc = MFMA(a1,  WKh[nb][1], acc, 0, 0, 0);
      acc = MFMA(a1,  WKl[nb][1], acc, 0, 0, 0);
      acc = MFMA(a1l, WKh[nb][1], acc, 0, 0, 0);
      dk[nb] = acc;
    }
    f32x4 dv = {0,0,0,0};
    dv = MFMA(a0,  WVh[0], dv, 0, 0, 0);
    dv = MFMA(a0,  WVl[0], dv, 0, 0, 0);
    dv = MFMA(a0l, WVh[0], dv, 0, 0, 0);
    dv = MFMA(a1,  WVh[1], dv, 0, 0, 0);
    dv = MFMA(a1,  WVl[1], dv, 0, 0, 0);
    dv = MFMA(a1l, WVh[1], dv, 0, 0, 0);
    float kh[4];
    focus(dk, kh);
    ksump += (kh[0] + kh[1]) + (kh[2] + kh[3]);
    const int tl2 = (16*wv + 4*g4) * 2;
    bf4v pk, pv;
#pragma unroll
    for (int r = 0; r < 4; ++r){ pk[r] = (short)f2bf(kh[r]); pv[r] = (short)f2bf(dv[r]); }
    *(bf4v*)((char*)kft + c15*256 + (tl2 ^ swz)) = pk;
    *(bf4v*)((char*)vtt + c15*256 + (tl2 ^ swz)) = pv;
    __syncthreads();
    if (wv == 0){
#pragma unroll
      for (int k2 = 0; k2 < 4; ++k2){
        const int tb = k2*64 + g4*16;
        bf8v af = *(const bf8v*)((char*)kft + c15*256 + (tb ^ swz));
        bf8v bf = *(const bf8v*)((char*)vtt + c15*256 + (tb ^ swz));
        kvacc = MFMA(af, bf, kvacc, 0, 0, 0);
      }
    }
  }
  __syncthreads();
  ksp[(wv*4 + g4)*16 + c15] = ksump;
  if (wv == 0){
#pragma unroll
    for (int r = 0; r < 4; ++r) kvf[(4*g4 + r)*16 + c15] = kvacc[r];
  }
  __syncthreads();
  if (tid < 16){
    float s = 0.0f;
    for (int j = 0; j < 32; ++j) s += ksp[j*16 + tid];
    ksh[tid] = s;
  }
  {
    const int d = tid >> 5, k = tid & 31;
    kvB[d*40 + k] = (k < 16) ? f2bf(kvf[k*16 + d]) : (u16)0;
  }
  __syncthreads();
  const bf8v  kvfrag = *(const bf8v*)((char*)kvB + c15*80 + g4*16);
  const float ksr    = ksh[c15];
  bf8v WQh[4][2], WQl[4][2];
#pragma unroll
  for (int nb = 0; nb < 4; ++nb)
#pragma unroll
    for (int kt = 0; kt < 2; ++kt)
      ldsplit(wqkv + (size_t)(nb*16 + c15)*64 + kt*32 + 8*g4, WQh[nb][kt], WQl[nb][kt]);
  float wdw[25], wge[9];
#pragma unroll
  for (int i = 0; i < 25; ++i) wdw[i] = wdwc[c15*25 + i];
#pragma unroll
  for (int i = 0; i < 9;  ++i) wge[i] = wgetv[(h*16 + c15)*9 + i];
  const float bdw = bdwc[c15];
  const float bge = bgetv[h*16 + c15];

  for (int tile = 0; tile < 16; ++tile){
    __syncthreads();
    load_x(tile*16 - 2, 20);
    __syncthreads();
    for (int mt = wv; mt < 10; mt += 8){
      bf8v va0  = read_af(16*mt, 0, 0);
      bf8v va1  = read_af(16*mt, 1, 0);
      bf8v va0l = read_af(16*mt, 0, 1);
      bf8v va1l = read_af(16*mt, 1, 1);
      f32x4 dv = {0,0,0,0};
      dv = MFMA(va0,  WVh[0], dv, 0, 0, 0);
      dv = MFMA(va0,  WVl[0], dv, 0, 0, 0);
      dv = MFMA(va0l, WVh[0], dv, 0, 0, 0);
      dv = MFMA(va1,  WVh[1], dv, 0, 0, 0);
      dv = MFMA(va1,  WVl[1], dv, 0, 0, 0);
      dv = MFMA(va1l, WVh[1], dv, 0, 0, 0);
      const int te = 16*mt + 4*g4;
      bf4v pv;
#pragma unroll
      for (int r = 0; r < 4; ++r) pv[r] = (short)f2bf(dv[r]);
      *(bf4v*)((char*)vt2 + c15*336 + (te >> 3)*16 + (te & 7)*2) = pv;
    }
    bf8v a0  = read_af(16 + 16*wv, 0, 0);
    bf8v a1  = read_af(16 + 16*wv, 1, 0);
    bf8v a0l = read_af(16 + 16*wv, 0, 1);
    bf8v a1l = read_af(16 + 16*wv, 1, 1);
    f32x4 dq[4];
#pragma unroll
    for (int nb = 0; nb < 4; ++nb){
      f32x4 acc = {0,0,0,0};
      acc = MFMA(a0,  WQh[nb][0], acc, 0, 0, 0);
      acc = MFMA(a0,  WQl[nb][0], acc, 0, 0, 0);
      acc = MFMA(a0l, WQh[nb][0], acc, 0, 0, 0);
      acc = MFMA(a1,  WQh[nb][1], acc, 0, 0, 0);
      acc = MFMA(a1,  WQl[nb][1], acc, 0, 0, 0);
      acc = MFMA(a1l, WQh[nb][1], acc, 0, 0, 0);
      dq[nb] = acc;
    }
    float qh[4];
    focus(dq, qh);
    float z[4];
#pragma unroll
    for (int r = 0; r < 4; ++r){
      float dot = rowsum16(qh[r] * ksr);
      z[r] = 1.0f / (dot + 1e-6f);
    }
    {
      const int base = wv*512 + (c15 >> 3)*256 + (c15 & 7)*2;
#pragma unroll
      for (int r = 0; r < 4; ++r)
        *(u16*)((char*)qfm + base + (4*g4 + r)*16) = f2bf(qh[r]);
    }
    __syncthreads();
    bf8v aq = *(const bf8v*)((char*)qfm + wv*512 + (g4 & 1)*256 + c15*16);
    f32x4 dat = {0,0,0,0};
    dat = MFMA(aq, kvfrag, dat, 0, 0, 0);
    const int  hsl = 2*wv + (g4 >> 1);
    const bool w0  = ((g4 & 1) == 0);
    float swv[5][8];
#pragma unroll
    for (int dy = 0; dy < 5; ++dy){
      bf8v rv = *(const bf8v*)((char*)vt2 + c15*336 + (hsl + dy)*16);
      float rf[8];
#pragma unroll
      for (int i = 0; i < 8; ++i) rf[i] = bf2f((u16)rv[i]);
      swv[dy][0] = w0 ? 0.0f : rf[2];
      swv[dy][1] = w0 ? 0.0f : rf[3];
      swv[dy][2] = w0 ? rf[0] : rf[4];
      swv[dy][3] = w0 ? rf[1] : rf[5];
      swv[dy][4] = w0 ? rf[2] : rf[6];
      swv[dy][5] = w0 ? rf[3] : rf[7];
      swv[dy][6] = w0 ? rf[4] : 0.0f;
      swv[dy][7] = w0 ? rf[5] : 0.0f;
    }
#pragma unroll
    for (int r = 0; r < 4; ++r){
      float accf = bdw;
#pragma unroll
      for (int dy = 0; dy < 5; ++dy)
#pragma unroll
        for (int dx = 0; dx < 5; ++dx)
          accf += swv[dy][r + dx] * wdw[dy*5 + dx];
      float accl = bge;
#pragma unroll
      for (int ky = 0; ky < 3; ++ky)
#pragma unroll
        for (int kx = 0; kx < 3; ++kx)
          accl += swv[1 + ky][r + 1 + kx] * wge[ky*3 + kx];
      const int    twin = tile*128 + 16*wv + 4*g4 + r;
      const size_t l    = (size_t)(twin >> 3) * 256 + wcol + (twin & 7);
      outg[xbase + l*64 + h*16 + c15] = dat[r] * z[r] + accf + accl;
    }
  }
}

extern "C" void kernel_launch(void* const* d_in, const int* in_sizes, int n_in,
                              void* d_out, int out_size, void* d_ws, size_t ws_size,
                              hipStream_t stream)
{
  (void)in_sizes; (void)n_in; (void)out_size;
  const float* xg     = (const float*)d_in[0];
  const float* wqkv   = (const float*)d_in[1];
  const float* wgetv  = (const float*)d_in[2];
  const float* bgetv  = (const float*)d_in[3];
  const float* wdwc   = (const float*)d_in[4];
  const float* bdwc   = (const float*)d_in[5];
  const float* scalep = (const float*)d_in[6];
  float* out = (float*)d_out;

  if (d_ws != nullptr && ws_size >= WS_NEED_BYTES){
    float* ws = (float*)d_ws;
    fla_k1<<<dim3(512), dim3(512), 0, stream>>>(xg, wqkv, scalep, ws);
    fla_k2<<<dim3(512), dim3(512), 0, stream>>>(xg, wqkv, wgetv, bgetv, wdwc, bdwc, scalep, ws, out);
  } else {
    fla_fused<<<dim3(512), dim3(512), 0, stream>>>(xg, wqkv, wgetv, bgetv, wdwc, bdwc, scalep, out);
  }
}

// Round 6
// 152.341 us; speedup vs baseline: 1.5673x; 1.2158x over previous
//
#include <hip/hip_runtime.h>

// FocusedLinearAttention — MI355X gfx950. f32 in/out (bf16-rounded values;
// threshold 2% of max|ref|). Round-6: head-deduplicated 2-kernel pipeline.
//   nk1 (window x quarter): x staged once (hi/lo bf16); focused-k -> partial
//       ksum/kv; focused-q -> qf bf16 in ws; v bf16 -> ws ([ch][token]).
//   nk2 (window x quarter): reduce partials; z + attention MFMA (qf read
//       directly from ws) + merged 5x5(+3x3) depthwise conv; store.
// Fallback (ws < 71.4 MB): validated round-5 pair (fla_k1/fla_k2, 185 us).
//
// MFMA layout (v_mfma_f32_16x16x32_bf16), HW-verified via round-3/5 passes:
//   A: lane l elem j -> A[m=l&15][k=8*(l>>4)+j]
//   B: lane l elem j -> B[k=8*(l>>4)+j][n=l&15]
//   D: lane l reg  r -> D[m=4*(l>>4)+r][n=l&15]

typedef float f32x4 __attribute__((ext_vector_type(4)));
typedef short bf8v  __attribute__((ext_vector_type(8)));
typedef short bf4v  __attribute__((ext_vector_type(4)));
typedef unsigned short u16;

#define MFMA __builtin_amdgcn_mfma_f32_16x16x32_bf16

static __device__ __forceinline__ u16 f2bf(float f){   // RTNE
  union { float f; unsigned int i; } v; v.f = f;
  return (u16)((v.i + 0x7FFFu + ((v.i >> 16) & 1u)) >> 16);
}
static __device__ __forceinline__ float bf2f(u16 u){
  union { unsigned int i; float f; } v; v.i = ((unsigned int)u) << 16; return v.f;
}
template<int CTRL>
static __device__ __forceinline__ float dppadd(float x){
  int m = __builtin_amdgcn_update_dpp(0, __builtin_bit_cast(int, x), CTRL, 0xF, 0xF, true);
  return x + __builtin_bit_cast(float, m);
}
static __device__ __forceinline__ float rowsum16(float x){
  x = dppadd<0x121>(x); x = dppadd<0x122>(x); x = dppadd<0x124>(x); x = dppadd<0x128>(x);
  return x;
}

// focus for all 4 channel groups of 4 tokens (lane = ch nb*16+c15, tok 4*g4+r)
static __device__ __forceinline__ void focus16(const f32x4 d[4], const float isc[4], float kh[4][4]){
  float s2[4] = {0,0,0,0}, s6[4] = {0,0,0,0};
#pragma unroll
  for (int nb = 0; nb < 4; ++nb)
#pragma unroll
    for (int r = 0; r < 4; ++r){
      float t = fmaxf(d[nb][r], 0.0f) + 1e-6f;
      t *= isc[nb];
      const float t2 = t * t;
      s2[r] += t2; s6[r] += t2 * t2 * t2;
      kh[nb][r] = t;
    }
#pragma unroll
  for (int r = 0; r < 4; ++r){
    const float f = sqrtf(rowsum16(s2[r]) / rowsum16(s6[r]));
#pragma unroll
    for (int nb = 0; nb < 4; ++nb){
      const float t = kh[nb][r];
      kh[nb][r] = t * t * t * f;
    }
  }
}

// ======== NEW-PATH workspace layout (byte offsets) ========
constexpr size_t NKV_OFF = 0;                   // f32 [128 wp][4 qt][8 slot][256]   (4 MB)
constexpr size_t NKS_OFF = 4194304;             // f32 [128 wp][4 qt][64 ch]         (128 KB)
constexpr size_t NQF_OFF = 4325376;             // u16 [262144 tok][64 ch] + 128 pad (33.55 MB)
constexpr size_t NV_OFF  = 37880064;            // u16 [64 ch][262144 tok]           (33.55 MB)
constexpr size_t NWS_NEED = 71434496;

// shared LDS geometry for nk1 / fla_k1
constexpr int A_XSH = 0;       // 128 tok x 128B bf16 hi (chunk-xor swizzle)
constexpr int A_XSL = 16384;   // lo plane
constexpr int A_KFT = 32768;   // [64 ch][128 tok] bf16, 256B rows, chunk-swizzled
constexpr int A_VTT = 49152;
constexpr int A_TOT = 65536;

// ======================= nk1 =======================
__global__ __launch_bounds__(512, 4)
void nk1(const float* __restrict__ xg, const float* __restrict__ wqkv,
         const float* __restrict__ scalep, float* __restrict__ ws)
{
  __shared__ __attribute__((aligned(16))) char smem[A_TOT];
  const int bid = blockIdx.x;
  const int qt = bid >> 7, wp = bid & 127;
  const int wcol = (wp & 31) * 8;
  const int tid = threadIdx.x, wv = tid >> 6, lane = tid & 63;
  const int g4 = lane >> 4, c15 = lane & 15;
  const size_t xbase = (size_t)(wp >> 5) * (65536ull * 64ull);
  const int swz = (c15 & 7) << 4;

  u16* qf_ws = (u16*)((char*)ws + NQF_OFF);
  u16* v_ws  = (u16*)((char*)ws + NV_OFF);

  // zero the qf tail pad (overread target of the last token's h=3 A-frag)
  if (bid == 0 && tid < 16){
    bf8v z8 = {0,0,0,0,0,0,0,0};
    *(bf8v*)(qf_ws + 262144ull*64ull + tid*8) = z8;
  }

  float isc[4];
#pragma unroll
  for (int nb = 0; nb < 4; ++nb) isc[nb] = 1.0f / logf(1.0f + expf(scalep[nb*16 + c15]));

  auto ldsplit = [&](const float* p, bf8v& hi, bf8v& lo){
    f32x4 u = *(const f32x4*)p;
    f32x4 w = *(const f32x4*)(p + 4);
#pragma unroll
    for (int j = 0; j < 4; ++j){
      u16 hb = f2bf(u[j]); hi[j]   = (short)hb; lo[j]   = (short)f2bf(u[j] - bf2f(hb));
      u16 hc = f2bf(w[j]); hi[4+j] = (short)hc; lo[4+j] = (short)f2bf(w[j] - bf2f(hc));
    }
  };
  auto loadA = [&](int t){
    const int row0 = qt*64 + t*16;                 // always in [0,256)
    for (int ci = tid; ci < 1024; ci += 512){
      const int te = ci >> 3, c8 = ci & 7;
      const float* p = xg + xbase + ((size_t)(row0 + (te >> 3)) * 256 + wcol + (te & 7)) * 64 + c8 * 8;
      bf8v vh, vl;
      f32x4 u = *(const f32x4*)p, w = *(const f32x4*)(p + 4);
#pragma unroll
      for (int j = 0; j < 4; ++j){
        u16 hb = f2bf(u[j]); vh[j]   = (short)hb; vl[j]   = (short)f2bf(u[j] - bf2f(hb));
        u16 hc = f2bf(w[j]); vh[4+j] = (short)hc; vl[4+j] = (short)f2bf(w[j] - bf2f(hc));
      }
      const int off = te * 128 + ((c8 ^ (te & 7)) << 4);
      *(bf8v*)(smem + A_XSH + off) = vh;
      *(bf8v*)(smem + A_XSL + off) = vl;
    }
  };
  auto rdA = [&](int plane, int tokbase, int cc) -> bf8v {
    const int te = tokbase + c15;
    return *(const bf8v*)(smem + plane + te * 128 + ((cc ^ (te & 7)) << 4));
  };

  // 6-MFMA double-bf16 GEMM, weight fragments reloaded from global (L1-hot)
  const float* wq_t = wqkv;
  auto gemm6 = [&](const float* wbase, int row, bf8v a0, bf8v a1, bf8v a0l, bf8v a1l) -> f32x4 {
    bf8v h0, l0, h1, l1;
    ldsplit(wbase + (size_t)row*64 + 8*g4,      h0, l0);
    ldsplit(wbase + (size_t)row*64 + 32 + 8*g4, h1, l1);
    f32x4 acc = {0,0,0,0};
    acc = MFMA(a0,  h0, acc, 0,0,0);
    acc = MFMA(a0,  l0, acc, 0,0,0);
    acc = MFMA(a0l, h0, acc, 0,0,0);
    acc = MFMA(a1,  h1, acc, 0,0,0);
    acc = MFMA(a1,  l1, acc, 0,0,0);
    acc = MFMA(a1l, h1, acc, 0,0,0);
    return acc;
  };

  float ksA[4] = {0,0,0,0};
  f32x4 kvacc = {0,0,0,0};
  const int kvhead = wv >> 1, kvs0 = (wv & 1) * 2;

#pragma unroll 1
  for (int tile = 0; tile < 4; ++tile){
    asm volatile("" : "+s"(wq_t));               // defeat LICM weight-frag hoisting
    __syncthreads();
    loadA(tile);
    __syncthreads();

    bf8v a0  = rdA(A_XSH, wv*16, g4),  a1  = rdA(A_XSH, wv*16, 4 + g4);
    bf8v a0l = rdA(A_XSL, wv*16, g4),  a1l = rdA(A_XSL, wv*16, 4 + g4);
    const int tglob = wp*2048 + qt*512 + tile*128 + wv*16 + 4*g4;
    const int tb2 = (wv*16 + 4*g4) * 2;          // token byte offset within kft/vtt plane

    // ---- k phase ----
    f32x4 d4[4];
#pragma unroll
    for (int nb = 0; nb < 4; ++nb) d4[nb] = gemm6(wq_t, 64 + nb*16 + c15, a0, a1, a0l, a1l);
    float kh[4][4];
    focus16(d4, isc, kh);
#pragma unroll
    for (int nb = 0; nb < 4; ++nb){
      ksA[nb] += (kh[nb][0] + kh[nb][1]) + (kh[nb][2] + kh[nb][3]);
      bf4v pk;
#pragma unroll
      for (int r = 0; r < 4; ++r) pk[r] = (short)f2bf(kh[nb][r]);
      *(bf4v*)(smem + A_KFT + (nb*16 + c15)*256 + (tb2 ^ swz)) = pk;
    }

    // ---- q phase ----
#pragma unroll
    for (int nb = 0; nb < 4; ++nb) d4[nb] = gemm6(wq_t, nb*16 + c15, a0, a1, a0l, a1l);
    focus16(d4, isc, kh);
#pragma unroll
    for (int nb = 0; nb < 4; ++nb)
#pragma unroll
      for (int r = 0; r < 4; ++r)
        qf_ws[(size_t)(tglob + r)*64 + nb*16 + c15] = f2bf(kh[nb][r]);

    // ---- v phase ----
#pragma unroll
    for (int nb = 0; nb < 4; ++nb){
      f32x4 acc = gemm6(wq_t, 128 + nb*16 + c15, a0, a1, a0l, a1l);
      bf4v pv;
#pragma unroll
      for (int r = 0; r < 4; ++r) pv[r] = (short)f2bf(acc[r]);
      *(bf4v*)(smem + A_VTT + (nb*16 + c15)*256 + (tb2 ^ swz)) = pv;
      *(bf4v*)(v_ws + (size_t)(nb*16 + c15)*262144 + tglob) = pv;
    }

    __syncthreads();
    // ---- kv: wave wv -> head wv>>1, token-chunks kvs0..kvs0+1 ----
#pragma unroll
    for (int s = 0; s < 2; ++s){
      const int tb = (kvs0 + s)*64 + g4*16;
      bf8v af = *(const bf8v*)(smem + A_KFT + (kvhead*16 + c15)*256 + (tb ^ swz));
      bf8v bv = *(const bf8v*)(smem + A_VTT + (kvhead*16 + c15)*256 + (tb ^ swz));
      kvacc = MFMA(af, bv, kvacc, 0,0,0);
    }
  }

  __syncthreads();
  float* ksp = (float*)smem;                     // reuse xs region
#pragma unroll
  for (int nb = 0; nb < 4; ++nb) ksp[(wv*4 + g4)*64 + nb*16 + c15] = ksA[nb];
  float* kvp = (float*)((char*)ws + NKV_OFF) + ((size_t)(wp*4 + qt)*8 + wv) * 256;
#pragma unroll
  for (int r = 0; r < 4; ++r) kvp[(4*g4 + r)*16 + c15] = kvacc[r];
  __syncthreads();
  if (tid < 64){
    float s = 0.0f;
    for (int j = 0; j < 32; ++j) s += ksp[j*64 + tid];
    ((float*)((char*)ws + NKS_OFF))[(wp*4 + qt)*64 + tid] = s;
  }
}

// ======================= nk2 =======================
constexpr int N_VT  = 0;       // [64 ch][21 slots][16B] bf16   (21504)
constexpr int N_ATT = 21504;   // [128 tok][168B] bf16 attn     (21504)
constexpr int N_KVB = 43008;   // [4 h][16 d][40 k] bf16        (5120)
constexpr int N_CMB = 48128;   // [64 ch][27] f32 comb weights  (6912)
constexpr int N_KSH = 55040;   // [64] f32 ksum                 (256)
constexpr int N_ZZ  = 55296;   // [4 h][128 tok] f32 z          (2048)
constexpr int N_TOT = 57344;

__global__ __launch_bounds__(512, 4)
void nk2(const float* __restrict__ wgetv, const float* __restrict__ bgetv,
         const float* __restrict__ wdwc,  const float* __restrict__ bdwc,
         const float* __restrict__ ws,    float* __restrict__ outg)
{
  __shared__ __attribute__((aligned(16))) char smem[N_TOT];
  const int bid = blockIdx.x;
  const int qt = bid >> 7, wp = bid & 127;
  const int wcol = (wp & 31) * 8;
  const int tid = threadIdx.x, wv = tid >> 6, lane = tid & 63;
  const int g4 = lane >> 4, c15 = lane & 15;
  const size_t xbase = (size_t)(wp >> 5) * (65536ull * 64ull);

  const u16*   qf_ws = (const u16*)((const char*)ws + NQF_OFF);
  const u16*   v_ws  = (const u16*)((const char*)ws + NV_OFF);
  const float* kv_ws = (const float*)((const char*)ws + NKV_OFF);
  const float* ks_ws = (const float*)((const char*)ws + NKS_OFF);
  u16*   vt   = (u16*)(smem + N_VT);
  u16*   att  = (u16*)(smem + N_ATT);
  u16*   kvb  = (u16*)(smem + N_KVB);
  float* cmb  = (float*)(smem + N_CMB);
  float* kshf = (float*)(smem + N_KSH);
  float* zz   = (float*)(smem + N_ZZ);

  // ---- prologue ----
  for (int e = tid; e < 64*27; e += 512){        // merged conv kernel + bias
    const int ch = e / 27, i = e - ch*27;
    float v = 0.0f;
    if (i < 25){
      const int dy = i / 5, dx = i - dy*5;
      v = wdwc[(ch & 15)*25 + i];
      if (dy >= 1 && dy <= 3 && dx >= 1 && dx <= 3)
        v += wgetv[ch*9 + (dy-1)*3 + (dx-1)];
    } else if (i == 25){
      v = bdwc[ch & 15] + bgetv[ch];
    }
    cmb[e] = v;
  }
  if (tid < 64){
    float s = 0.0f;
#pragma unroll
    for (int q2 = 0; q2 < 4; ++q2) s += ks_ws[(wp*4 + q2)*64 + tid];
    kshf[tid] = s;
  }
  for (int e = tid; e < 2560; e += 512){         // kvB [h][d][40], k>=16 zero
    const int h2 = e / 640, rem = e - h2*640, d = rem / 40, k = rem - d*40;
    u16 val = 0;
    if (k < 16){
      float s = 0.0f;
#pragma unroll
      for (int q2 = 0; q2 < 4; ++q2)
#pragma unroll
        for (int sl = 0; sl < 2; ++sl)
          s += kv_ws[((size_t)(wp*4 + q2)*8 + h2*2 + sl)*256 + k*16 + d];
      val = f2bf(s);
    }
    kvb[e] = val;
  }
  __syncthreads();

#pragma unroll 1
  for (int tile = 0; tile < 4; ++tile){
    const int tile_r0 = qt*64 + tile*16;
    const int t_base  = wp*2048 + qt*512 + tile*128;
    __syncthreads();

    // stage v tile (+/-2 halo rows; OOB rows -> 0)
    for (int c = tid; c < 1280; c += 512){
      const int ch = c / 20, slot = c - ch*20;
      const int grow = tile_r0 - 2 + slot;
      bf8v val = {0,0,0,0,0,0,0,0};
      if ((unsigned)grow < 256u)
        val = *(const bf8v*)(v_ws + (size_t)ch*262144 + wp*2048 + grow*8);
      *(bf8v*)((char*)vt + ch*336 + slot*16) = val;
    }
    // z pass: thread -> (token, head)
    {
      const int tokL = tid >> 2, hz = tid & 3;
      const size_t qo = (size_t)(t_base + tokL)*64 + hz*16;
      bf8v qa = *(const bf8v*)(qf_ws + qo);
      bf8v qb = *(const bf8v*)(qf_ws + qo + 8);
      float dot = 0.0f;
#pragma unroll
      for (int j = 0; j < 8; ++j){
        dot += bf2f((u16)qa[j]) * kshf[hz*16 + j];
        dot += bf2f((u16)qb[j]) * kshf[hz*16 + 8 + j];
      }
      zz[hz*128 + tokL] = 1.0f / (dot + 1e-6f);
    }
    __syncthreads();

    // attention: wave wv owns tokens wv*16..+15; one MFMA per head
#pragma unroll
    for (int nb = 0; nb < 4; ++nb){
      bf8v aq = *(const bf8v*)(qf_ws + (size_t)(t_base + wv*16 + c15)*64 + nb*16 + g4*8);
      bf8v bq = *(const bf8v*)(kvb + nb*640 + c15*40 + g4*8);
      f32x4 dat = {0,0,0,0};
      dat = MFMA(aq, bq, dat, 0,0,0);
#pragma unroll
      for (int r = 0; r < 4; ++r){
        const int tokL = wv*16 + 4*g4 + r;
        att[tokL*84 + nb*16 + c15] = f2bf(dat[r] * zz[nb*128 + tokL]);
      }
    }
    __syncthreads();

    // conv: lane = channel (0..63), wave = 2 output rows
    {
      const int ch = lane;
      float cb[26];
#pragma unroll
      for (int i = 0; i < 26; ++i) cb[i] = cmb[ch*27 + i];
      float rf[6][8];
#pragma unroll
      for (int j = 0; j < 6; ++j){
        bf8v rv = *(const bf8v*)((char*)vt + ch*336 + (wv*2 + j)*16);
#pragma unroll
        for (int i = 0; i < 8; ++i) rf[j][i] = bf2f((u16)rv[i]);
      }
#pragma unroll
      for (int o = 0; o < 2; ++o){
        float acc[8];
#pragma unroll
        for (int s = 0; s < 8; ++s) acc[s] = cb[25];
#pragma unroll
        for (int dy = 0; dy < 5; ++dy)
#pragma unroll
          for (int dx = 0; dx < 5; ++dx){
            const float w = cb[dy*5 + dx];
#pragma unroll
            for (int s = 0; s < 8; ++s){
              const int c = s + dx - 2;
              if (c >= 0 && c < 8) acc[s] += rf[o + dy][c] * w;
            }
          }
        const int tok0 = (wv*2 + o)*8;
        const size_t obase = xbase + ((size_t)(tile_r0 + wv*2 + o)*256 + wcol)*64 + ch;
#pragma unroll
        for (int s = 0; s < 8; ++s)
          outg[obase + (size_t)s*64] = acc[s] + bf2f(att[(tok0 + s)*84 + ch]);
      }
    }
  }
}

// ======================= round-5 fallback pair (validated) =======================
constexpr int    WS_KV = 0;            // [128 wp][4 qt][4 h][16 kch][16 vch] f32
constexpr int    WS_KS = 524288;       // [128 wp][4 qt][64 ch] f32
constexpr size_t WS_NEED_BYTES = (524288ull + 32768ull) * 4ull;

__global__ __launch_bounds__(512, 2)
void fla_k1(const float* __restrict__ xg, const float* __restrict__ wqkv,
            const float* __restrict__ scalep, float* __restrict__ ws)
{
  __shared__ __attribute__((aligned(16))) char smem[A_TOT];
  const int bid = blockIdx.x;
  const int qt = bid >> 7, wp = bid & 127;
  const int b = wp >> 5, wcol = (wp & 31) * 8;
  const int tid = threadIdx.x, wv = tid >> 6, lane = tid & 63;
  const int g4 = lane >> 4, c15 = lane & 15;
  const size_t xbase = (size_t)b * (65536ull * 64ull);
  const int swz = (c15 & 7) << 4;

  auto ldsplit = [&](const float* p, bf8v& hi, bf8v& lo){
    f32x4 u = *(const f32x4*)p;
    f32x4 w = *(const f32x4*)(p + 4);
#pragma unroll
    for (int j = 0; j < 4; ++j){
      u16 hb = f2bf(u[j]); hi[j]   = (short)hb; lo[j]   = (short)f2bf(u[j] - bf2f(hb));
      u16 hc = f2bf(w[j]); hi[4+j] = (short)hc; lo[4+j] = (short)f2bf(w[j] - bf2f(hc));
    }
  };
  auto loadA = [&](int t){
    const int row0 = qt*64 + t*16;
    for (int ci = tid; ci < 1024; ci += 512){
      const int te = ci >> 3, c8 = ci & 7;
      const float* p = xg + xbase + ((size_t)(row0 + (te >> 3)) * 256 + wcol + (te & 7)) * 64 + c8 * 8;
      bf8v vh, vl;
      f32x4 u = *(const f32x4*)p, w = *(const f32x4*)(p + 4);
#pragma unroll
      for (int j = 0; j < 4; ++j){
        u16 hb = f2bf(u[j]); vh[j]   = (short)hb; vl[j]   = (short)f2bf(u[j] - bf2f(hb));
        u16 hc = f2bf(w[j]); vh[4+j] = (short)hc; vl[4+j] = (short)f2bf(w[j] - bf2f(hc));
      }
      const int off = te * 128 + ((c8 ^ (te & 7)) << 4);
      *(bf8v*)(smem + A_XSH + off) = vh;
      *(bf8v*)(smem + A_XSL + off) = vl;
    }
  };
  auto rdA = [&](int plane, int tokbase, int cc) -> bf8v {
    const int te = tokbase + c15;
    return *(const bf8v*)(smem + plane + te * 128 + ((cc ^ (te & 7)) << 4));
  };

  if (wv < 4){
    float isc[4];
#pragma unroll
    for (int nb = 0; nb < 4; ++nb) isc[nb] = 1.0f / logf(1.0f + expf(scalep[nb*16 + c15]));
    bf8v WKh[4][2], WKl[4][2];
#pragma unroll
    for (int nb = 0; nb < 4; ++nb)
#pragma unroll
      for (int kt = 0; kt < 2; ++kt)
        ldsplit(wqkv + (size_t)(64 + nb*16 + c15)*64 + kt*32 + 8*g4, WKh[nb][kt], WKl[nb][kt]);

    float ksA[4] = {0,0,0,0};
    f32x4 kvacc = {0,0,0,0};
    for (int t = 0; t < 4; ++t){
      __syncthreads();
      loadA(t);
      __syncthreads();
#pragma unroll
      for (int s = 0; s < 2; ++s){
        const int tg = wv*2 + s;
        bf8v a0  = rdA(A_XSH, tg*16, g4),  a1  = rdA(A_XSH, tg*16, 4 + g4);
        bf8v a0l = rdA(A_XSL, tg*16, g4),  a1l = rdA(A_XSL, tg*16, 4 + g4);
        f32x4 dk[4];
#pragma unroll
        for (int nb = 0; nb < 4; ++nb){
          f32x4 acc = {0,0,0,0};
          acc = MFMA(a0,  WKh[nb][0], acc, 0,0,0);
          acc = MFMA(a0,  WKl[nb][0], acc, 0,0,0);
          acc = MFMA(a0l, WKh[nb][0], acc, 0,0,0);
          acc = MFMA(a1,  WKh[nb][1], acc, 0,0,0);
          acc = MFMA(a1,  WKl[nb][1], acc, 0,0,0);
          acc = MFMA(a1l, WKh[nb][1], acc, 0,0,0);
          dk[nb] = acc;
        }
        float kh[4][4];
        focus16(dk, isc, kh);
        const int tb2 = (tg*16 + 4*g4) * 2;
#pragma unroll
        for (int nb = 0; nb < 4; ++nb){
          ksA[nb] += (kh[nb][0] + kh[nb][1]) + (kh[nb][2] + kh[nb][3]);
          bf4v pk;
#pragma unroll
          for (int r = 0; r < 4; ++r) pk[r] = (short)f2bf(kh[nb][r]);
          *(bf4v*)(smem + A_KFT + (nb*16 + c15)*256 + (tb2 ^ swz)) = pk;
        }
      }
      __syncthreads();
#pragma unroll
      for (int k2 = 0; k2 < 4; ++k2){
        const int tb = k2*64 + g4*16;
        bf8v af = *(const bf8v*)(smem + A_KFT + (wv*16 + c15)*256 + (tb ^ swz));
        bf8v bv = *(const bf8v*)(smem + A_VTT + (wv*16 + c15)*256 + (tb ^ swz));
        kvacc = MFMA(af, bv, kvacc, 0,0,0);
      }
    }
    __syncthreads();
    float* ksp = (float*)smem;
#pragma unroll
    for (int nb = 0; nb < 4; ++nb) ksp[(wv*4 + g4)*64 + nb*16 + c15] = ksA[nb];
    float* kvp = ws + WS_KV + ((wp*4 + qt)*4 + wv) * 256;
#pragma unroll
    for (int r = 0; r < 4; ++r) kvp[(4*g4 + r)*16 + c15] = kvacc[r];
  } else {
    bf8v WVh[4][2], WVl[4][2];
#pragma unroll
    for (int nb = 0; nb < 4; ++nb)
#pragma unroll
      for (int kt = 0; kt < 2; ++kt)
        ldsplit(wqkv + (size_t)(128 + nb*16 + c15)*64 + kt*32 + 8*g4, WVh[nb][kt], WVl[nb][kt]);

    for (int t = 0; t < 4; ++t){
      __syncthreads();
      loadA(t);
      __syncthreads();
#pragma unroll
      for (int s = 0; s < 2; ++s){
        const int tg = (wv - 4)*2 + s;
        bf8v a0  = rdA(A_XSH, tg*16, g4),  a1  = rdA(A_XSH, tg*16, 4 + g4);
        bf8v a0l = rdA(A_XSL, tg*16, g4),  a1l = rdA(A_XSL, tg*16, 4 + g4);
        const int tb2 = (tg*16 + 4*g4) * 2;
#pragma unroll
        for (int nb = 0; nb < 4; ++nb){
          f32x4 acc = {0,0,0,0};
          acc = MFMA(a0,  WVh[nb][0], acc, 0,0,0);
          acc = MFMA(a0,  WVl[nb][0], acc, 0,0,0);
          acc = MFMA(a0l, WVh[nb][0], acc, 0,0,0);
          acc = MFMA(a1,  WVh[nb][1], acc, 0,0,0);
          acc = MFMA(a1,  WVl[nb][1], acc, 0,0,0);
          acc = MFMA(a1l, WVh[nb][1], acc, 0,0,0);
          bf4v pv;
#pragma unroll
          for (int r = 0; r < 4; ++r) pv[r] = (short)f2bf(acc[r]);
          *(bf4v*)(smem + A_VTT + (nb*16 + c15)*256 + (tb2 ^ swz)) = pv;
        }
      }
      __syncthreads();
    }
    __syncthreads();
  }
  __syncthreads();
  if (tid < 64){
    const float* ksp = (const float*)smem;
    float s = 0.0f;
    for (int j = 0; j < 16; ++j) s += ksp[j*64 + tid];
    ws[WS_KS + (wp*4 + qt)*64 + tid] = s;
  }
}

constexpr int LDS_X   = 0;
constexpr int LDS_VT2 = 49152;
constexpr int LDS_QFM = 54528;
constexpr int LDS_KVB = 58624;
constexpr int LDS_KSH = 62976;
constexpr int LDS_TOT = 63040;

__global__ __launch_bounds__(512, 2)
void fla_k2(const float* __restrict__ xg,   const float* __restrict__ wqkv,
            const float* __restrict__ wgetv,const float* __restrict__ bgetv,
            const float* __restrict__ wdwc, const float* __restrict__ bdwc,
            const float* __restrict__ scalep, const float* __restrict__ ws,
            float* __restrict__ outg)
{
  __shared__ __attribute__((aligned(16))) char smem[LDS_TOT];
  u16*   xs  = (u16*)(smem + LDS_X);
  u16*   vt2 = (u16*)(smem + LDS_VT2);
  u16*   qfm = (u16*)(smem + LDS_QFM);
  u16*   kvB = (u16*)(smem + LDS_KVB);
  float* ksh = (float*)(smem + LDS_KSH);

  const int bid  = blockIdx.x;
  const int h    = bid >> 7;
  const int wp   = bid & 127;
  const int b    = wp >> 5;
  const int wcol = (wp & 31) * 8;
  const int tid  = threadIdx.x;
  const int wv   = tid >> 6;
  const int lane = tid & 63;
  const int g4   = lane >> 4;
  const int c15  = lane & 15;
  const size_t xbase = (size_t)b * (65536ull * 64ull);

  float isc[4];
#pragma unroll
  for (int nb = 0; nb < 4; ++nb){
    float p = scalep[nb*16 + c15];
    isc[nb] = 1.0f / logf(1.0f + expf(p));
  }
  auto ldsplit = [&](const float* p, bf8v& hi, bf8v& lo){
    f32x4 u = *(const f32x4*)p;
    f32x4 w = *(const f32x4*)(p + 4);
#pragma unroll
    for (int j = 0; j < 4; ++j){
      u16 hb = f2bf(u[j]); hi[j]   = (short)hb; lo[j]   = (short)f2bf(u[j] - bf2f(hb));
      u16 hc = f2bf(w[j]); hi[4+j] = (short)hc; lo[4+j] = (short)f2bf(w[j] - bf2f(hc));
    }
  };
  bf8v WVh[2], WVl[2];
#pragma unroll
  for (int kt = 0; kt < 2; ++kt)
    ldsplit(wqkv + (size_t)(128 + h*16 + c15)*64 + kt*32 + 8*g4, WVh[kt], WVl[kt]);

  auto load_x = [&](int row0, int nrows){
    const int total = nrows * 64;
    for (int ci = tid; ci < total; ci += 512){
      const int te = ci >> 3;
      const int c8 = ci & 7;
      const int hs = row0 + (te >> 3);
      bf8v vh = {0,0,0,0,0,0,0,0}, vl = {0,0,0,0,0,0,0,0};
      if (hs >= 0 && hs < 256){
        const size_t l = (size_t)hs * 256 + wcol + (te & 7);
        const float* p = xg + xbase + l*64 + c8*8;
        f32x4 u = *(const f32x4*)p;
        f32x4 w = *(const f32x4*)(p + 4);
#pragma unroll
        for (int j = 0; j < 4; ++j){
          u16 hb = f2bf(u[j]); vh[j]   = (short)hb; vl[j]   = (short)f2bf(u[j] - bf2f(hb));
          u16 hc = f2bf(w[j]); vh[4+j] = (short)hc; vl[4+j] = (short)f2bf(w[j] - bf2f(hc));
        }
      }
      const int off = te*128 + ((c8 ^ (te & 7)) << 4);
      *(bf8v*)((char*)xs + off)         = vh;
      *(bf8v*)((char*)xs + 20480 + off) = vl;
    }
  };
  auto read_af = [&](int rowbase, int kt, int plane) -> bf8v {
    const int te = rowbase + c15;
    const int cc = kt*4 + g4;
    return *(const bf8v*)((char*)xs + plane*20480 + te*128 + ((cc ^ (te & 7)) << 4));
  };
  auto focus = [&](const f32x4* dmat, float* fh){
    float s2[4] = {0,0,0,0}, s6[4] = {0,0,0,0};
    float h1[4], h2[4];
#pragma unroll
    for (int nb = 0; nb < 4; ++nb){
#pragma unroll
      for (int r = 0; r < 4; ++r){
        float t = fmaxf(dmat[nb][r], 0.0f) + 1e-6f;
        t *= isc[nb];
        float t2 = t * t;
        s2[r] += t2;
        s6[r] += t2 * t2 * t2;
        if (nb == h){ h1[r] = t; h2[r] = t2; }
      }
    }
#pragma unroll
    for (int r = 0; r < 4; ++r){
      float a2 = rowsum16(s2[r]);
      float a6 = rowsum16(s6[r]);
      float f  = sqrtf(a2 / a6);
      fh[r] = h1[r] * h2[r] * f;
    }
  };

  if (tid < 16){
    float s = 0.0f;
#pragma unroll
    for (int q2 = 0; q2 < 4; ++q2) s += ws[WS_KS + (wp*4 + q2)*64 + h*16 + tid];
    ksh[tid] = s;
  }
  {
    const int d = tid >> 5, k = tid & 31;
    float s = 0.0f;
    if (k < 16){
#pragma unroll
      for (int q2 = 0; q2 < 4; ++q2) s += ws[WS_KV + ((wp*4 + q2)*4 + h)*256 + k*16 + d];
    }
    kvB[d*40 + k] = (k < 16) ? f2bf(s) : (u16)0;
  }
  __syncthreads();

  const bf8v  kvfrag = *(const bf8v*)((char*)kvB + c15*80 + g4*16);
  const float ksr    = ksh[c15];

  bf8v WQh[4][2], WQl[4][2];
#pragma unroll
  for (int nb = 0; nb < 4; ++nb)
#pragma unroll
    for (int kt = 0; kt < 2; ++kt)
      ldsplit(wqkv + (size_t)(nb*16 + c15)*64 + kt*32 + 8*g4, WQh[nb][kt], WQl[nb][kt]);
  float wdw[25], wge[9];
#pragma unroll
  for (int i = 0; i < 25; ++i) wdw[i] = wdwc[c15*25 + i];
#pragma unroll
  for (int i = 0; i < 9;  ++i) wge[i] = wgetv[(h*16 + c15)*9 + i];
  const float bdw = bdwc[c15];
  const float bge = bgetv[h*16 + c15];

  for (int tile = 0; tile < 16; ++tile){
    __syncthreads();
    load_x(tile*16 - 2, 20);
    __syncthreads();

    for (int mt = wv; mt < 10; mt += 8){
      bf8v va0  = read_af(16*mt, 0, 0);
      bf8v va1  = read_af(16*mt, 1, 0);
      bf8v va0l = read_af(16*mt, 0, 1);
      bf8v va1l = read_af(16*mt, 1, 1);
      f32x4 dv = {0,0,0,0};
      dv = MFMA(va0,  WVh[0], dv, 0, 0, 0);
      dv = MFMA(va0,  WVl[0], dv, 0, 0, 0);
      dv = MFMA(va0l, WVh[0], dv, 0, 0, 0);
      dv = MFMA(va1,  WVh[1], dv, 0, 0, 0);
      dv = MFMA(va1,  WVl[1], dv, 0, 0, 0);
      dv = MFMA(va1l, WVh[1], dv, 0, 0, 0);
      const int te = 16*mt + 4*g4;
      bf4v pv;
#pragma unroll
      for (int r = 0; r < 4; ++r) pv[r] = (short)f2bf(dv[r]);
      *(bf4v*)((char*)vt2 + c15*336 + (te >> 3)*16 + (te & 7)*2) = pv;
    }

    bf8v a0  = read_af(16 + 16*wv, 0, 0);
    bf8v a1  = read_af(16 + 16*wv, 1, 0);
    bf8v a0l = read_af(16 + 16*wv, 0, 1);
    bf8v a1l = read_af(16 + 16*wv, 1, 1);
    f32x4 dq[4];
#pragma unroll
    for (int nb = 0; nb < 4; ++nb){
      f32x4 acc = {0,0,0,0};
      acc = MFMA(a0,  WQh[nb][0], acc, 0, 0, 0);
      acc = MFMA(a0,  WQl[nb][0], acc, 0, 0, 0);
      acc = MFMA(a0l, WQh[nb][0], acc, 0, 0, 0);
      acc = MFMA(a1,  WQh[nb][1], acc, 0, 0, 0);
      acc = MFMA(a1,  WQl[nb][1], acc, 0, 0, 0);
      acc = MFMA(a1l, WQh[nb][1], acc, 0, 0, 0);
      dq[nb] = acc;
    }
    float qh[4];
    focus(dq, qh);
    float z[4];
#pragma unroll
    for (int r = 0; r < 4; ++r){
      float dot = rowsum16(qh[r] * ksr);
      z[r] = 1.0f / (dot + 1e-6f);
    }
    {
      const int base = wv*512 + (c15 >> 3)*256 + (c15 & 7)*2;
#pragma unroll
      for (int r = 0; r < 4; ++r)
        *(u16*)((char*)qfm + base + (4*g4 + r)*16) = f2bf(qh[r]);
    }

    __syncthreads();

    bf8v aq = *(const bf8v*)((char*)qfm + wv*512 + (g4 & 1)*256 + c15*16);
    f32x4 dat = {0,0,0,0};
    dat = MFMA(aq, kvfrag, dat, 0, 0, 0);

    const int  hsl = 2*wv + (g4 >> 1);
    const bool w0  = ((g4 & 1) == 0);
    float swv[5][8];
#pragma unroll
    for (int dy = 0; dy < 5; ++dy){
      bf8v rv = *(const bf8v*)((char*)vt2 + c15*336 + (hsl + dy)*16);
      float rf[8];
#pragma unroll
      for (int i = 0; i < 8; ++i) rf[i] = bf2f((u16)rv[i]);
      swv[dy][0] = w0 ? 0.0f : rf[2];
      swv[dy][1] = w0 ? 0.0f : rf[3];
      swv[dy][2] = w0 ? rf[0] : rf[4];
      swv[dy][3] = w0 ? rf[1] : rf[5];
      swv[dy][4] = w0 ? rf[2] : rf[6];
      swv[dy][5] = w0 ? rf[3] : rf[7];
      swv[dy][6] = w0 ? rf[4] : 0.0f;
      swv[dy][7] = w0 ? rf[5] : 0.0f;
    }

#pragma unroll
    for (int r = 0; r < 4; ++r){
      float accf = bdw;
#pragma unroll
      for (int dy = 0; dy < 5; ++dy)
#pragma unroll
        for (int dx = 0; dx < 5; ++dx)
          accf += swv[dy][r + dx] * wdw[dy*5 + dx];
      float accl = bge;
#pragma unroll
      for (int ky = 0; ky < 3; ++ky)
#pragma unroll
        for (int kx = 0; kx < 3; ++kx)
          accl += swv[1 + ky][r + 1 + kx] * wge[ky*3 + kx];
      const int    twin = tile*128 + 16*wv + 4*g4 + r;
      const size_t l    = (size_t)(twin >> 3) * 256 + wcol + (twin & 7);
      outg[xbase + l*64 + h*16 + c15] = dat[r] * z[r] + accf + accl;
    }
  }
}

extern "C" void kernel_launch(void* const* d_in, const int* in_sizes, int n_in,
                              void* d_out, int out_size, void* d_ws, size_t ws_size,
                              hipStream_t stream)
{
  (void)in_sizes; (void)n_in; (void)out_size;
  const float* xg     = (const float*)d_in[0];
  const float* wqkv   = (const float*)d_in[1];
  const float* wgetv  = (const float*)d_in[2];
  const float* bgetv  = (const float*)d_in[3];
  const float* wdwc   = (const float*)d_in[4];
  const float* bdwc   = (const float*)d_in[5];
  const float* scalep = (const float*)d_in[6];
  float* out = (float*)d_out;
  float* ws  = (float*)d_ws;

  if (d_ws != nullptr && ws_size >= NWS_NEED){
    nk1<<<dim3(512), dim3(512), 0, stream>>>(xg, wqkv, scalep, ws);
    nk2<<<dim3(512), dim3(512), 0, stream>>>(wgetv, bgetv, wdwc, bdwc, ws, out);
  } else {
    fla_k1<<<dim3(512), dim3(512), 0, stream>>>(xg, wqkv, scalep, ws);
    fla_k2<<<dim3(512), dim3(512), 0, stream>>>(xg, wqkv, wgetv, bgetv, wdwc, bdwc, scalep, ws, out);
  }
}

// Round 8
// 150.642 us; speedup vs baseline: 1.5849x; 1.0113x over previous
//
#include <hip/hip_runtime.h>

// FocusedLinearAttention — MI355X gfx950. f32 in/out (bf16-rounded values;
// threshold 2% of max|ref|). Round-8: round-6 pipeline VERBATIM (all staging
// and packing via the validated f2bf bit-trick; cvt_pk asm removed — it
// correlates 2/2 with NaN failures) + ONE change: nk0 pre-splits w_qkv into
// bf16 hi/lo planes in ws, nk1 reads weight fragments as 16B loads (kills
// ~8.4k VALU ops/thread of per-call weight re-splitting, round-6's measured
// bottleneck: VALUBusy 50%, 122 us).
//
// MFMA layout (v_mfma_f32_16x16x32_bf16), HW-verified via round-3/5/6 passes:
//   A: lane l elem j -> A[m=l&15][k=8*(l>>4)+j]
//   B: lane l elem j -> B[k=8*(l>>4)+j][n=l&15]
//   D: lane l reg  r -> D[m=4*(l>>4)+r][n=l&15]

typedef float f32x4 __attribute__((ext_vector_type(4)));
typedef short bf8v  __attribute__((ext_vector_type(8)));
typedef short bf4v  __attribute__((ext_vector_type(4)));
typedef unsigned short u16;

#define MFMA __builtin_amdgcn_mfma_f32_16x16x32_bf16

static __device__ __forceinline__ u16 f2bf(float f){   // RTNE bit-trick (validated)
  union { float f; unsigned int i; } v; v.f = f;
  return (u16)((v.i + 0x7FFFu + ((v.i >> 16) & 1u)) >> 16);
}
static __device__ __forceinline__ float bf2f(u16 u){
  union { unsigned int i; float f; } v; v.i = ((unsigned int)u) << 16; return v.f;
}
template<int CTRL>
static __device__ __forceinline__ float dppadd(float x){
  int m = __builtin_amdgcn_update_dpp(0, __builtin_bit_cast(int, x), CTRL, 0xF, 0xF, true);
  return x + __builtin_bit_cast(float, m);
}
static __device__ __forceinline__ float rowsum16(float x){
  x = dppadd<0x121>(x); x = dppadd<0x122>(x); x = dppadd<0x124>(x); x = dppadd<0x128>(x);
  return x;
}

// focus for all 4 channel groups of 4 tokens (lane = ch nb*16+c15, tok 4*g4+r)
static __device__ __forceinline__ void focus16(const f32x4 d[4], const float isc[4], float kh[4][4]){
  float s2[4] = {0,0,0,0}, s6[4] = {0,0,0,0};
#pragma unroll
  for (int nb = 0; nb < 4; ++nb)
#pragma unroll
    for (int r = 0; r < 4; ++r){
      float t = fmaxf(d[nb][r], 0.0f) + 1e-6f;
      t *= isc[nb];
      const float t2 = t * t;
      s2[r] += t2; s6[r] += t2 * t2 * t2;
      kh[nb][r] = t;
    }
#pragma unroll
  for (int r = 0; r < 4; ++r){
    const float f = sqrtf(rowsum16(s2[r]) / rowsum16(s6[r]));
#pragma unroll
    for (int nb = 0; nb < 4; ++nb){
      const float t = kh[nb][r];
      kh[nb][r] = t * t * t * f;
    }
  }
}

// ======== NEW-PATH workspace layout (byte offsets) ========
constexpr size_t NKV_OFF = 0;                   // f32 [128 wp][4 qt][8 slot][256]   (4 MB)
constexpr size_t NKS_OFF = 4194304;             // f32 [128 wp][4 qt][64 ch]         (128 KB)
constexpr size_t NQF_OFF = 4325376;             // u16 [262144 tok][64 ch] + 128 pad (33.55 MB)
constexpr size_t NV_OFF  = 37880064;            // u16 [64 ch][262144 tok]           (33.55 MB)
constexpr size_t NW_OFF  = 71434496;            // u16 [2][192][64] w_qkv hi/lo      (49 KB)
constexpr size_t NWS_NEED  = 71434496;
constexpr size_t NWS_NEED2 = 71483648;

// shared LDS geometry for nk1 / fla_k1
constexpr int A_XSH = 0;       // 128 tok x 128B bf16 hi (chunk-xor swizzle)
constexpr int A_XSL = 16384;   // lo plane
constexpr int A_KFT = 32768;   // [64 ch][128 tok] bf16, 256B rows, chunk-swizzled
constexpr int A_VTT = 49152;
constexpr int A_TOT = 65536;

// ======================= nk0: one-time weight hi/lo split =======================
__global__ __launch_bounds__(512, 8)
void nk0(const float* __restrict__ wqkv, float* __restrict__ ws)
{
  u16* wsp = (u16*)((char*)ws + NW_OFF);
  const int e = blockIdx.x * 512 + threadIdx.x;   // grid 24 -> 12288 exactly
  const float f = wqkv[e];
  const u16 hb = f2bf(f);
  wsp[e]         = hb;
  wsp[12288 + e] = f2bf(f - bf2f(hb));
}

// ======================= nk1 =======================
template<bool PRE>
__global__ __launch_bounds__(512, 4)
void nk1(const float* __restrict__ xg, const float* __restrict__ wqkv,
         const float* __restrict__ scalep, float* __restrict__ ws)
{
  __shared__ __attribute__((aligned(16))) char smem[A_TOT];
  const int bid = blockIdx.x;
  const int qt = bid >> 7, wp = bid & 127;
  const int wcol = (wp & 31) * 8;
  const int tid = threadIdx.x, wv = tid >> 6, lane = tid & 63;
  const int g4 = lane >> 4, c15 = lane & 15;
  const size_t xbase = (size_t)(wp >> 5) * (65536ull * 64ull);
  const int swz = (c15 & 7) << 4;

  u16* qf_ws = (u16*)((char*)ws + NQF_OFF);
  u16* v_ws  = (u16*)((char*)ws + NV_OFF);
  const u16* wsp = (const u16*)((const char*)ws + NW_OFF);

  // zero the qf tail pad (overread target of the last token's h=3 A-frag)
  if (bid == 0 && tid < 16){
    bf8v z8 = {0,0,0,0,0,0,0,0};
    *(bf8v*)(qf_ws + 262144ull*64ull + tid*8) = z8;
  }

  float isc[4];
#pragma unroll
  for (int nb = 0; nb < 4; ++nb) isc[nb] = 1.0f / logf(1.0f + expf(scalep[nb*16 + c15]));

  auto ldsplit = [&](const float* p, bf8v& hi, bf8v& lo){
    f32x4 u = *(const f32x4*)p;
    f32x4 w = *(const f32x4*)(p + 4);
#pragma unroll
    for (int j = 0; j < 4; ++j){
      u16 hb = f2bf(u[j]); hi[j]   = (short)hb; lo[j]   = (short)f2bf(u[j] - bf2f(hb));
      u16 hc = f2bf(w[j]); hi[4+j] = (short)hc; lo[4+j] = (short)f2bf(w[j] - bf2f(hc));
    }
  };
  // loadA: VERBATIM round-6 (validated)
  auto loadA = [&](int t){
    const int row0 = qt*64 + t*16;                 // always in [0,256)
    for (int ci = tid; ci < 1024; ci += 512){
      const int te = ci >> 3, c8 = ci & 7;
      const float* p = xg + xbase + ((size_t)(row0 + (te >> 3)) * 256 + wcol + (te & 7)) * 64 + c8 * 8;
      bf8v vh, vl;
      f32x4 u = *(const f32x4*)p, w = *(const f32x4*)(p + 4);
#pragma unroll
      for (int j = 0; j < 4; ++j){
        u16 hb = f2bf(u[j]); vh[j]   = (short)hb; vl[j]   = (short)f2bf(u[j] - bf2f(hb));
        u16 hc = f2bf(w[j]); vh[4+j] = (short)hc; vl[4+j] = (short)f2bf(w[j] - bf2f(hc));
      }
      const int off = te * 128 + ((c8 ^ (te & 7)) << 4);
      *(bf8v*)(smem + A_XSH + off) = vh;
      *(bf8v*)(smem + A_XSL + off) = vl;
    }
  };
  auto rdA = [&](int plane, int tokbase, int cc) -> bf8v {
    const int te = tokbase + c15;
    return *(const bf8v*)(smem + plane + te * 128 + ((cc ^ (te & 7)) << 4));
  };

  // 6-MFMA double-bf16 GEMM; PRE: weight frags are 16B loads from ws planes
  const float* wq_t  = wqkv;
  const u16*   wsp_t = wsp;
  auto gemm6 = [&](int row, bf8v a0, bf8v a1, bf8v a0l, bf8v a1l) -> f32x4 {
    bf8v h0, l0, h1, l1;
    if constexpr (PRE){
      const u16* pb = wsp_t + row*64 + 8*g4;
      h0 = *(const bf8v*)(pb);
      h1 = *(const bf8v*)(pb + 32);
      l0 = *(const bf8v*)(pb + 12288);
      l1 = *(const bf8v*)(pb + 12288 + 32);
    } else {
      ldsplit(wq_t + (size_t)row*64 + 8*g4,      h0, l0);
      ldsplit(wq_t + (size_t)row*64 + 32 + 8*g4, h1, l1);
    }
    f32x4 acc = {0,0,0,0};
    acc = MFMA(a0,  h0, acc, 0,0,0);
    acc = MFMA(a0,  l0, acc, 0,0,0);
    acc = MFMA(a0l, h0, acc, 0,0,0);
    acc = MFMA(a1,  h1, acc, 0,0,0);
    acc = MFMA(a1,  l1, acc, 0,0,0);
    acc = MFMA(a1l, h1, acc, 0,0,0);
    return acc;
  };

  float ksA[4] = {0,0,0,0};
  f32x4 kvacc = {0,0,0,0};
  const int kvhead = wv >> 1, kvs0 = (wv & 1) * 2;

#pragma unroll 1
  for (int tile = 0; tile < 4; ++tile){
    asm volatile("" : "+s"(wq_t), "+s"(wsp_t));  // defeat LICM weight-frag hoisting
    __syncthreads();
    loadA(tile);
    __syncthreads();

    bf8v a0  = rdA(A_XSH, wv*16, g4),  a1  = rdA(A_XSH, wv*16, 4 + g4);
    bf8v a0l = rdA(A_XSL, wv*16, g4),  a1l = rdA(A_XSL, wv*16, 4 + g4);
    const int tglob = wp*2048 + qt*512 + tile*128 + wv*16 + 4*g4;
    const int tb2 = (wv*16 + 4*g4) * 2;          // token byte offset within kft/vtt plane

    // ---- k phase ----
    f32x4 d4[4];
#pragma unroll
    for (int nb = 0; nb < 4; ++nb) d4[nb] = gemm6(64 + nb*16 + c15, a0, a1, a0l, a1l);
    float kh[4][4];
    focus16(d4, isc, kh);
#pragma unroll
    for (int nb = 0; nb < 4; ++nb){
      ksA[nb] += (kh[nb][0] + kh[nb][1]) + (kh[nb][2] + kh[nb][3]);
      bf4v pk;
#pragma unroll
      for (int r = 0; r < 4; ++r) pk[r] = (short)f2bf(kh[nb][r]);
      *(bf4v*)(smem + A_KFT + (nb*16 + c15)*256 + (tb2 ^ swz)) = pk;
    }

    // ---- q phase ----
#pragma unroll
    for (int nb = 0; nb < 4; ++nb) d4[nb] = gemm6(nb*16 + c15, a0, a1, a0l, a1l);
    focus16(d4, isc, kh);
#pragma unroll
    for (int nb = 0; nb < 4; ++nb)
#pragma unroll
      for (int r = 0; r < 4; ++r)
        qf_ws[(size_t)(tglob + r)*64 + nb*16 + c15] = f2bf(kh[nb][r]);

    // ---- v phase ----
#pragma unroll
    for (int nb = 0; nb < 4; ++nb){
      f32x4 acc = gemm6(128 + nb*16 + c15, a0, a1, a0l, a1l);
      bf4v pv;
#pragma unroll
      for (int r = 0; r < 4; ++r) pv[r] = (short)f2bf(acc[r]);
      *(bf4v*)(smem + A_VTT + (nb*16 + c15)*256 + (tb2 ^ swz)) = pv;
      *(bf4v*)(v_ws + (size_t)(nb*16 + c15)*262144 + tglob) = pv;
    }

    __syncthreads();
    // ---- kv: wave wv -> head wv>>1, token-chunks kvs0..kvs0+1 ----
#pragma unroll
    for (int s = 0; s < 2; ++s){
      const int tb = (kvs0 + s)*64 + g4*16;
      bf8v af = *(const bf8v*)(smem + A_KFT + (kvhead*16 + c15)*256 + (tb ^ swz));
      bf8v bv = *(const bf8v*)(smem + A_VTT + (kvhead*16 + c15)*256 + (tb ^ swz));
      kvacc = MFMA(af, bv, kvacc, 0,0,0);
    }
  }

  __syncthreads();
  float* ksp = (float*)smem;                     // reuse xs region
#pragma unroll
  for (int nb = 0; nb < 4; ++nb) ksp[(wv*4 + g4)*64 + nb*16 + c15] = ksA[nb];
  float* kvp = (float*)((char*)ws + NKV_OFF) + ((size_t)(wp*4 + qt)*8 + wv) * 256;
#pragma unroll
  for (int r = 0; r < 4; ++r) kvp[(4*g4 + r)*16 + c15] = kvacc[r];
  __syncthreads();
  if (tid < 64){
    float s = 0.0f;
    for (int j = 0; j < 32; ++j) s += ksp[j*64 + tid];
    ((float*)((char*)ws + NKS_OFF))[(wp*4 + qt)*64 + tid] = s;
  }
}

// ======================= nk2 (VERBATIM round 6, validated) =======================
constexpr int N_VT  = 0;       // [64 ch][21 slots][16B] bf16   (21504)
constexpr int N_ATT = 21504;   // [128 tok][168B] bf16 attn     (21504)
constexpr int N_KVB = 43008;   // [4 h][16 d][40 k] bf16        (5120)
constexpr int N_CMB = 48128;   // [64 ch][27] f32 comb weights  (6912)
constexpr int N_KSH = 55040;   // [64] f32 ksum                 (256)
constexpr int N_ZZ  = 55296;   // [4 h][128 tok] f32 z          (2048)
constexpr int N_TOT = 57344;

__global__ __launch_bounds__(512, 4)
void nk2(const float* __restrict__ wgetv, const float* __restrict__ bgetv,
         const float* __restrict__ wdwc,  const float* __restrict__ bdwc,
         const float* __restrict__ ws,    float* __restrict__ outg)
{
  __shared__ __attribute__((aligned(16))) char smem[N_TOT];
  const int bid = blockIdx.x;
  const int qt = bid >> 7, wp = bid & 127;
  const int wcol = (wp & 31) * 8;
  const int tid = threadIdx.x, wv = tid >> 6, lane = tid & 63;
  const int g4 = lane >> 4, c15 = lane & 15;
  const size_t xbase = (size_t)(wp >> 5) * (65536ull * 64ull);

  const u16*   qf_ws = (const u16*)((const char*)ws + NQF_OFF);
  const u16*   v_ws  = (const u16*)((const char*)ws + NV_OFF);
  const float* kv_ws = (const float*)((const char*)ws + NKV_OFF);
  const float* ks_ws = (const float*)((const char*)ws + NKS_OFF);
  u16*   vt   = (u16*)(smem + N_VT);
  u16*   att  = (u16*)(smem + N_ATT);
  u16*   kvb  = (u16*)(smem + N_KVB);
  float* cmb  = (float*)(smem + N_CMB);
  float* kshf = (float*)(smem + N_KSH);
  float* zz   = (float*)(smem + N_ZZ);

  for (int e = tid; e < 64*27; e += 512){
    const int ch = e / 27, i = e - ch*27;
    float v = 0.0f;
    if (i < 25){
      const int dy = i / 5, dx = i - dy*5;
      v = wdwc[(ch & 15)*25 + i];
      if (dy >= 1 && dy <= 3 && dx >= 1 && dx <= 3)
        v += wgetv[ch*9 + (dy-1)*3 + (dx-1)];
    } else if (i == 25){
      v = bdwc[ch & 15] + bgetv[ch];
    }
    cmb[e] = v;
  }
  if (tid < 64){
    float s = 0.0f;
#pragma unroll
    for (int q2 = 0; q2 < 4; ++q2) s += ks_ws[(wp*4 + q2)*64 + tid];
    kshf[tid] = s;
  }
  for (int e = tid; e < 2560; e += 512){
    const int h2 = e / 640, rem = e - h2*640, d = rem / 40, k = rem - d*40;
    u16 val = 0;
    if (k < 16){
      float s = 0.0f;
#pragma unroll
      for (int q2 = 0; q2 < 4; ++q2)
#pragma unroll
        for (int sl = 0; sl < 2; ++sl)
          s += kv_ws[((size_t)(wp*4 + q2)*8 + h2*2 + sl)*256 + k*16 + d];
      val = f2bf(s);
    }
    kvb[e] = val;
  }
  __syncthreads();

#pragma unroll 1
  for (int tile = 0; tile < 4; ++tile){
    const int tile_r0 = qt*64 + tile*16;
    const int t_base  = wp*2048 + qt*512 + tile*128;
    __syncthreads();

    for (int c = tid; c < 1280; c += 512){
      const int ch = c / 20, slot = c - ch*20;
      const int grow = tile_r0 - 2 + slot;
      bf8v val = {0,0,0,0,0,0,0,0};
      if ((unsigned)grow < 256u)
        val = *(const bf8v*)(v_ws + (size_t)ch*262144 + wp*2048 + grow*8);
      *(bf8v*)((char*)vt + ch*336 + slot*16) = val;
    }
    {
      const int tokL = tid >> 2, hz = tid & 3;
      const size_t qo = (size_t)(t_base + tokL)*64 + hz*16;
      bf8v qa = *(const bf8v*)(qf_ws + qo);
      bf8v qb = *(const bf8v*)(qf_ws + qo + 8);
      float dot = 0.0f;
#pragma unroll
      for (int j = 0; j < 8; ++j){
        dot += bf2f((u16)qa[j]) * kshf[hz*16 + j];
        dot += bf2f((u16)qb[j]) * kshf[hz*16 + 8 + j];
      }
      zz[hz*128 + tokL] = 1.0f / (dot + 1e-6f);
    }
    __syncthreads();

#pragma unroll
    for (int nb = 0; nb < 4; ++nb){
      bf8v aq = *(const bf8v*)(qf_ws + (size_t)(t_base + wv*16 + c15)*64 + nb*16 + g4*8);
      bf8v bq = *(const bf8v*)(kvb + nb*640 + c15*40 + g4*8);
      f32x4 dat = {0,0,0,0};
      dat = MFMA(aq, bq, dat, 0,0,0);
#pragma unroll
      for (int r = 0; r < 4; ++r){
        const int tokL = wv*16 + 4*g4 + r;
        att[tokL*84 + nb*16 + c15] = f2bf(dat[r] * zz[nb*128 + tokL]);
      }
    }
    __syncthreads();

    {
      const int ch = lane;
      float cb[26];
#pragma unroll
      for (int i = 0; i < 26; ++i) cb[i] = cmb[ch*27 + i];
      float rf[6][8];
#pragma unroll
      for (int j = 0; j < 6; ++j){
        bf8v rv = *(const bf8v*)((char*)vt + ch*336 + (wv*2 + j)*16);
#pragma unroll
        for (int i = 0; i < 8; ++i) rf[j][i] = bf2f((u16)rv[i]);
      }
#pragma unroll
      for (int o = 0; o < 2; ++o){
        float acc[8];
#pragma unroll
        for (int s = 0; s < 8; ++s) acc[s] = cb[25];
#pragma unroll
        for (int dy = 0; dy < 5; ++dy)
#pragma unroll
          for (int dx = 0; dx < 5; ++dx){
            const float w = cb[dy*5 + dx];
#pragma unroll
            for (int s = 0; s < 8; ++s){
              const int c = s + dx - 2;
              if (c >= 0 && c < 8) acc[s] += rf[o + dy][c] * w;
            }
          }
        const int tok0 = (wv*2 + o)*8;
        const size_t obase = xbase + ((size_t)(tile_r0 + wv*2 + o)*256 + wcol)*64 + ch;
#pragma unroll
        for (int s = 0; s < 8; ++s)
          outg[obase + (size_t)s*64] = acc[s] + bf2f(att[(tok0 + s)*84 + ch]);
      }
    }
  }
}

// ======================= round-5 fallback pair (validated) =======================
constexpr int    WS_KV = 0;
constexpr int    WS_KS = 524288;
constexpr size_t WS_NEED_BYTES = (524288ull + 32768ull) * 4ull;

__global__ __launch_bounds__(512, 2)
void fla_k1(const float* __restrict__ xg, const float* __restrict__ wqkv,
            const float* __restrict__ scalep, float* __restrict__ ws)
{
  __shared__ __attribute__((aligned(16))) char smem[A_TOT];
  const int bid = blockIdx.x;
  const int qt = bid >> 7, wp = bid & 127;
  const int b = wp >> 5, wcol = (wp & 31) * 8;
  const int tid = threadIdx.x, wv = tid >> 6, lane = tid & 63;
  const int g4 = lane >> 4, c15 = lane & 15;
  const size_t xbase = (size_t)b * (65536ull * 64ull);
  const int swz = (c15 & 7) << 4;

  auto ldsplit = [&](const float* p, bf8v& hi, bf8v& lo){
    f32x4 u = *(const f32x4*)p;
    f32x4 w = *(const f32x4*)(p + 4);
#pragma unroll
    for (int j = 0; j < 4; ++j){
      u16 hb = f2bf(u[j]); hi[j]   = (short)hb; lo[j]   = (short)f2bf(u[j] - bf2f(hb));
      u16 hc = f2bf(w[j]); hi[4+j] = (short)hc; lo[4+j] = (short)f2bf(w[j] - bf2f(hc));
    }
  };
  auto loadA = [&](int t){
    const int row0 = qt*64 + t*16;
    for (int ci = tid; ci < 1024; ci += 512){
      const int te = ci >> 3, c8 = ci & 7;
      const float* p = xg + xbase + ((size_t)(row0 + (te >> 3)) * 256 + wcol + (te & 7)) * 64 + c8 * 8;
      bf8v vh, vl;
      f32x4 u = *(const f32x4*)p, w = *(const f32x4*)(p + 4);
#pragma unroll
      for (int j = 0; j < 4; ++j){
        u16 hb = f2bf(u[j]); vh[j]   = (short)hb; vl[j]   = (short)f2bf(u[j] - bf2f(hb));
        u16 hc = f2bf(w[j]); vh[4+j] = (short)hc; vl[4+j] = (short)f2bf(w[j] - bf2f(hc));
      }
      const int off = te * 128 + ((c8 ^ (te & 7)) << 4);
      *(bf8v*)(smem + A_XSH + off) = vh;
      *(bf8v*)(smem + A_XSL + off) = vl;
    }
  };
  auto rdA = [&](int plane, int tokbase, int cc) -> bf8v {
    const int te = tokbase + c15;
    return *(const bf8v*)(smem + plane + te * 128 + ((cc ^ (te & 7)) << 4));
  };

  if (wv < 4){
    float isc[4];
#pragma unroll
    for (int nb = 0; nb < 4; ++nb) isc[nb] = 1.0f / logf(1.0f + expf(scalep[nb*16 + c15]));
    bf8v WKh[4][2], WKl[4][2];
#pragma unroll
    for (int nb = 0; nb < 4; ++nb)
#pragma unroll
      for (int kt = 0; kt < 2; ++kt)
        ldsplit(wqkv + (size_t)(64 + nb*16 + c15)*64 + kt*32 + 8*g4, WKh[nb][kt], WKl[nb][kt]);

    float ksA[4] = {0,0,0,0};
    f32x4 kvacc = {0,0,0,0};
    for (int t = 0; t < 4; ++t){
      __syncthreads();
      loadA(t);
      __syncthreads();
#pragma unroll
      for (int s = 0; s < 2; ++s){
        const int tg = wv*2 + s;
        bf8v a0  = rdA(A_XSH, tg*16, g4),  a1  = rdA(A_XSH, tg*16, 4 + g4);
        bf8v a0l = rdA(A_XSL, tg*16, g4),  a1l = rdA(A_XSL, tg*16, 4 + g4);
        f32x4 dk[4];
#pragma unroll
        for (int nb = 0; nb < 4; ++nb){
          f32x4 acc = {0,0,0,0};
          acc = MFMA(a0,  WKh[nb][0], acc, 0,0,0);
          acc = MFMA(a0,  WKl[nb][0], acc, 0,0,0);
          acc = MFMA(a0l, WKh[nb][0], acc, 0,0,0);
          acc = MFMA(a1,  WKh[nb][1], acc, 0,0,0);
          acc = MFMA(a1,  WKl[nb][1], acc, 0,0,0);
          acc = MFMA(a1l, WKh[nb][1], acc, 0,0,0);
          dk[nb] = acc;
        }
        float kh[4][4];
        focus16(dk, isc, kh);
        const int tb2 = (tg*16 + 4*g4) * 2;
#pragma unroll
        for (int nb = 0; nb < 4; ++nb){
          ksA[nb] += (kh[nb][0] + kh[nb][1]) + (kh[nb][2] + kh[nb][3]);
          bf4v pk;
#pragma unroll
          for (int r = 0; r < 4; ++r) pk[r] = (short)f2bf(kh[nb][r]);
          *(bf4v*)(smem + A_KFT + (nb*16 + c15)*256 + (tb2 ^ swz)) = pk;
        }
      }
      __syncthreads();
#pragma unroll
      for (int k2 = 0; k2 < 4; ++k2){
        const int tb = k2*64 + g4*16;
        bf8v af = *(const bf8v*)(smem + A_KFT + (wv*16 + c15)*256 + (tb ^ swz));
        bf8v bv = *(const bf8v*)(smem + A_VTT + (wv*16 + c15)*256 + (tb ^ swz));
        kvacc = MFMA(af, bv, kvacc, 0,0,0);
      }
    }
    __syncthreads();
    float* ksp = (float*)smem;
#pragma unroll
    for (int nb = 0; nb < 4; ++nb) ksp[(wv*4 + g4)*64 + nb*16 + c15] = ksA[nb];
    float* kvp = ws + WS_KV + ((wp*4 + qt)*4 + wv) * 256;
#pragma unroll
    for (int r = 0; r < 4; ++r) kvp[(4*g4 + r)*16 + c15] = kvacc[r];
  } else {
    bf8v WVh[4][2], WVl[4][2];
#pragma unroll
    for (int nb = 0; nb < 4; ++nb)
#pragma unroll
      for (int kt = 0; kt < 2; ++kt)
        ldsplit(wqkv + (size_t)(128 + nb*16 + c15)*64 + kt*32 + 8*g4, WVh[nb][kt], WVl[nb][kt]);

    for (int t = 0; t < 4; ++t){
      __syncthreads();
      loadA(t);
      __syncthreads();
#pragma unroll
      for (int s = 0; s < 2; ++s){
        const int tg = (wv - 4)*2 + s;
        bf8v a0  = rdA(A_XSH, tg*16, g4),  a1  = rdA(A_XSH, tg*16, 4 + g4);
        bf8v a0l = rdA(A_XSL, tg*16, g4),  a1l = rdA(A_XSL, tg*16, 4 + g4);
        const int tb2 = (tg*16 + 4*g4) * 2;
#pragma unroll
        for (int nb = 0; nb < 4; ++nb){
          f32x4 acc = {0,0,0,0};
          acc = MFMA(a0,  WVh[nb][0], acc, 0,0,0);
          acc = MFMA(a0,  WVl[nb][0], acc, 0,0,0);
          acc = MFMA(a0l, WVh[nb][0], acc, 0,0,0);
          acc = MFMA(a1,  WVh[nb][1], acc, 0,0,0);
          acc = MFMA(a1,  WVl[nb][1], acc, 0,0,0);
          acc = MFMA(a1l, WVh[nb][1], acc, 0,0,0);
          bf4v pv;
#pragma unroll
          for (int r = 0; r < 4; ++r) pv[r] = (short)f2bf(acc[r]);
          *(bf4v*)(smem + A_VTT + (nb*16 + c15)*256 + (tb2 ^ swz)) = pv;
        }
      }
      __syncthreads();
    }
    __syncthreads();
  }
  __syncthreads();
  if (tid < 64){
    const float* ksp = (const float*)smem;
    float s = 0.0f;
    for (int j = 0; j < 16; ++j) s += ksp[j*64 + tid];
    ws[WS_KS + (wp*4 + qt)*64 + tid] = s;
  }
}

constexpr int LDS_X   = 0;
constexpr int LDS_VT2 = 49152;
constexpr int LDS_QFM = 54528;
constexpr int LDS_KVB = 58624;
constexpr int LDS_KSH = 62976;
constexpr int LDS_TOT = 63040;

__global__ __launch_bounds__(512, 2)
void fla_k2(const float* __restrict__ xg,   const float* __restrict__ wqkv,
            const float* __restrict__ wgetv,const float* __restrict__ bgetv,
            const float* __restrict__ wdwc, const float* __restrict__ bdwc,
            const float* __restrict__ scalep, const float* __restrict__ ws,
            float* __restrict__ outg)
{
  __shared__ __attribute__((aligned(16))) char smem[LDS_TOT];
  u16*   xs  = (u16*)(smem + LDS_X);
  u16*   vt2 = (u16*)(smem + LDS_VT2);
  u16*   qfm = (u16*)(smem + LDS_QFM);
  u16*   kvB = (u16*)(smem + LDS_KVB);
  float* ksh = (float*)(smem + LDS_KSH);

  const int bid  = blockIdx.x;
  const int h    = bid >> 7;
  const int wp   = bid & 127;
  const int b    = wp >> 5;
  const int wcol = (wp & 31) * 8;
  const int tid  = threadIdx.x;
  const int wv   = tid >> 6;
  const int lane = tid & 63;
  const int g4   = lane >> 4;
  const int c15  = lane & 15;
  const size_t xbase = (size_t)b * (65536ull * 64ull);

  float isc[4];
#pragma unroll
  for (int nb = 0; nb < 4; ++nb){
    float p = scalep[nb*16 + c15];
    isc[nb] = 1.0f / logf(1.0f + expf(p));
  }
  auto ldsplit = [&](const float* p, bf8v& hi, bf8v& lo){
    f32x4 u = *(const f32x4*)p;
    f32x4 w = *(const f32x4*)(p + 4);
#pragma unroll
    for (int j = 0; j < 4; ++j){
      u16 hb = f2bf(u[j]); hi[j]   = (short)hb; lo[j]   = (short)f2bf(u[j] - bf2f(hb));
      u16 hc = f2bf(w[j]); hi[4+j] = (short)hc; lo[4+j] = (short)f2bf(w[j] - bf2f(hc));
    }
  };
  bf8v WVh[2], WVl[2];
#pragma unroll
  for (int kt = 0; kt < 2; ++kt)
    ldsplit(wqkv + (size_t)(128 + h*16 + c15)*64 + kt*32 + 8*g4, WVh[kt], WVl[kt]);

  auto load_x = [&](int row0, int nrows){
    const int total = nrows * 64;
    for (int ci = tid; ci < total; ci += 512){
      const int te = ci >> 3;
      const int c8 = ci & 7;
      const int hs = row0 + (te >> 3);
      bf8v vh = {0,0,0,0,0,0,0,0}, vl = {0,0,0,0,0,0,0,0};
      if (hs >= 0 && hs < 256){
        const size_t l = (size_t)hs * 256 + wcol + (te & 7);
        const float* p = xg + xbase + l*64 + c8*8;
        f32x4 u = *(const f32x4*)p;
        f32x4 w = *(const f32x4*)(p + 4);
#pragma unroll
        for (int j = 0; j < 4; ++j){
          u16 hb = f2bf(u[j]); vh[j]   = (short)hb; vl[j]   = (short)f2bf(u[j] - bf2f(hb));
          u16 hc = f2bf(w[j]); vh[4+j] = (short)hc; vl[4+j] = (short)f2bf(w[j] - bf2f(hc));
        }
      }
      const int off = te*128 + ((c8 ^ (te & 7)) << 4);
      *(bf8v*)((char*)xs + off)         = vh;
      *(bf8v*)((char*)xs + 20480 + off) = vl;
    }
  };
  auto read_af = [&](int rowbase, int kt, int plane) -> bf8v {
    const int te = rowbase + c15;
    const int cc = kt*4 + g4;
    return *(const bf8v*)((char*)xs + plane*20480 + te*128 + ((cc ^ (te & 7)) << 4));
  };
  auto focus = [&](const f32x4* dmat, float* fh){
    float s2[4] = {0,0,0,0}, s6[4] = {0,0,0,0};
    float h1[4], h2[4];
#pragma unroll
    for (int nb = 0; nb < 4; ++nb){
#pragma unroll
      for (int r = 0; r < 4; ++r){
        float t = fmaxf(dmat[nb][r], 0.0f) + 1e-6f;
        t *= isc[nb];
        float t2 = t * t;
        s2[r] += t2;
        s6[r] += t2 * t2 * t2;
        if (nb == h){ h1[r] = t; h2[r] = t2; }
      }
    }
#pragma unroll
    for (int r = 0; r < 4; ++r){
      float a2 = rowsum16(s2[r]);
      float a6 = rowsum16(s6[r]);
      float f  = sqrtf(a2 / a6);
      fh[r] = h1[r] * h2[r] * f;
    }
  };

  if (tid < 16){
    float s = 0.0f;
#pragma unroll
    for (int q2 = 0; q2 < 4; ++q2) s += ws[WS_KS + (wp*4 + q2)*64 + h*16 + tid];
    ksh[tid] = s;
  }
  {
    const int d = tid >> 5, k = tid & 31;
    float s = 0.0f;
    if (k < 16){
#pragma unroll
      for (int q2 = 0; q2 < 4; ++q2) s += ws[WS_KV + ((wp*4 + q2)*4 + h)*256 + k*16 + d];
    }
    kvB[d*40 + k] = (k < 16) ? f2bf(s) : (u16)0;
  }
  __syncthreads();

  const bf8v  kvfrag = *(const bf8v*)((char*)kvB + c15*80 + g4*16);
  const float ksr    = ksh[c15];

  bf8v WQh[4][2], WQl[4][2];
#pragma unroll
  for (int nb = 0; nb < 4; ++nb)
#pragma unroll
    for (int kt = 0; kt < 2; ++kt)
      ldsplit(wqkv + (size_t)(nb*16 + c15)*64 + kt*32 + 8*g4, WQh[nb][kt], WQl[nb][kt]);
  float wdw[25], wge[9];
#pragma unroll
  for (int i = 0; i < 25; ++i) wdw[i] = wdwc[c15*25 + i];
#pragma unroll
  for (int i = 0; i < 9;  ++i) wge[i] = wgetv[(h*16 + c15)*9 + i];
  const float bdw = bdwc[c15];
  const float bge = bgetv[h*16 + c15];

  for (int tile = 0; tile < 16; ++tile){
    __syncthreads();
    load_x(tile*16 - 2, 20);
    __syncthreads();

    for (int mt = wv; mt < 10; mt += 8){
      bf8v va0  = read_af(16*mt, 0, 0);
      bf8v va1  = read_af(16*mt, 1, 0);
      bf8v va0l = read_af(16*mt, 0, 1);
      bf8v va1l = read_af(16*mt, 1, 1);
      f32x4 dv = {0,0,0,0};
      dv = MFMA(va0,  WVh[0], dv, 0, 0, 0);
      dv = MFMA(va0,  WVl[0], dv, 0, 0, 0);
      dv = MFMA(va0l, WVh[0], dv, 0, 0, 0);
      dv = MFMA(va1,  WVh[1], dv, 0, 0, 0);
      dv = MFMA(va1,  WVl[1], dv, 0, 0, 0);
      dv = MFMA(va1l, WVh[1], dv, 0, 0, 0);
      const int te = 16*mt + 4*g4;
      bf4v pv;
#pragma unroll
      for (int r = 0; r < 4; ++r) pv[r] = (short)f2bf(dv[r]);
      *(bf4v*)((char*)vt2 + c15*336 + (te >> 3)*16 + (te & 7)*2) = pv;
    }

    bf8v a0  = read_af(16 + 16*wv, 0, 0);
    bf8v a1  = read_af(16 + 16*wv, 1, 0);
    bf8v a0l = read_af(16 + 16*wv, 0, 1);
    bf8v a1l = read_af(16 + 16*wv, 1, 1);
    f32x4 dq[4];
#pragma unroll
    for (int nb = 0; nb < 4; ++nb){
      f32x4 acc = {0,0,0,0};
      acc = MFMA(a0,  WQh[nb][0], acc, 0, 0, 0);
      acc = MFMA(a0,  WQl[nb][0], acc, 0, 0, 0);
      acc = MFMA(a0l, WQh[nb][0], acc, 0, 0, 0);
      acc = MFMA(a1,  WQh[nb][1], acc, 0, 0, 0);
      acc = MFMA(a1,  WQl[nb][1], acc, 0, 0, 0);
      acc = MFMA(a1l, WQh[nb][1], acc, 0, 0, 0);
      dq[nb] = acc;
    }
    float qh[4];
    focus(dq, qh);
    float z[4];
#pragma unroll
    for (int r = 0; r < 4; ++r){
      float dot = rowsum16(qh[r] * ksr);
      z[r] = 1.0f / (dot + 1e-6f);
    }
    {
      const int base = wv*512 + (c15 >> 3)*256 + (c15 & 7)*2;
#pragma unroll
      for (int r = 0; r < 4; ++r)
        *(u16*)((char*)qfm + base + (4*g4 + r)*16) = f2bf(qh[r]);
    }

    __syncthreads();

    bf8v aq = *(const bf8v*)((char*)qfm + wv*512 + (g4 & 1)*256 + c15*16);
    f32x4 dat = {0,0,0,0};
    dat = MFMA(aq, kvfrag, dat, 0, 0, 0);

    const int  hsl = 2*wv + (g4 >> 1);
    const bool w0  = ((g4 & 1) == 0);
    float swv[5][8];
#pragma unroll
    for (int dy = 0; dy < 5; ++dy){
      bf8v rv = *(const bf8v*)((char*)vt2 + c15*336 + (hsl + dy)*16);
      float rf[8];
#pragma unroll
      for (int i = 0; i < 8; ++i) rf[i] = bf2f((u16)rv[i]);
      swv[dy][0] = w0 ? 0.0f : rf[2];
      swv[dy][1] = w0 ? 0.0f : rf[3];
      swv[dy][2] = w0 ? rf[0] : rf[4];
      swv[dy][3] = w0 ? rf[1] : rf[5];
      swv[dy][4] = w0 ? rf[2] : rf[6];
      swv[dy][5] = w0 ? rf[3] : rf[7];
      swv[dy][6] = w0 ? rf[4] : 0.0f;
      swv[dy][7] = w0 ? rf[5] : 0.0f;
    }

#pragma unroll
    for (int r = 0; r < 4; ++r){
      float accf = bdw;
#pragma unroll
      for (int dy = 0; dy < 5; ++dy)
#pragma unroll
        for (int dx = 0; dx < 5; ++dx)
          accf += swv[dy][r + dx] * wdw[dy*5 + dx];
      float accl = bge;
#pragma unroll
      for (int ky = 0; ky < 3; ++ky)
#pragma unroll
        for (int kx = 0; kx < 3; ++kx)
          accl += swv[1 + ky][r + 1 + kx] * wge[ky*3 + kx];
      const int    twin = tile*128 + 16*wv + 4*g4 + r;
      const size_t l    = (size_t)(twin >> 3) * 256 + wcol + (twin & 7);
      outg[xbase + l*64 + h*16 + c15] = dat[r] * z[r] + accf + accl;
    }
  }
}

extern "C" void kernel_launch(void* const* d_in, const int* in_sizes, int n_in,
                              void* d_out, int out_size, void* d_ws, size_t ws_size,
                              hipStream_t stream)
{
  (void)in_sizes; (void)n_in; (void)out_size;
  const float* xg     = (const float*)d_in[0];
  const float* wqkv   = (const float*)d_in[1];
  const float* wgetv  = (const float*)d_in[2];
  const float* bgetv  = (const float*)d_in[3];
  const float* wdwc   = (const float*)d_in[4];
  const float* bdwc   = (const float*)d_in[5];
  const float* scalep = (const float*)d_in[6];
  float* out = (float*)d_out;
  float* ws  = (float*)d_ws;

  if (d_ws != nullptr && ws_size >= NWS_NEED2){
    nk0<<<dim3(24), dim3(512), 0, stream>>>(wqkv, ws);
    nk1<true><<<dim3(512), dim3(512), 0, stream>>>(xg, wqkv, scalep, ws);
    nk2<<<dim3(512), dim3(512), 0, stream>>>(wgetv, bgetv, wdwc, bdwc, ws, out);
  } else if (d_ws != nullptr && ws_size >= NWS_NEED){
    nk1<false><<<dim3(512), dim3(512), 0, stream>>>(xg, wqkv, scalep, ws);
    nk2<<<dim3(512), dim3(512), 0, stream>>>(wgetv, bgetv, wdwc, bdwc, ws, out);
  } else {
    fla_k1<<<dim3(512), dim3(512), 0, stream>>>(xg, wqkv, scalep, ws);
    fla_k2<<<dim3(512), dim3(512), 0, stream>>>(xg, wqkv, wgetv, bgetv, wdwc, bdwc, scalep, ws, out);
  }
}